// Round 1
// baseline (2094.529 us; speedup 1.0000x reference)
//
#include <hip/hip_runtime.h>
#include <math.h>

#define LNUM 2
#define BBATCH 4
#define TSEQ 1000
#define CDIM 768
#define HHEADS 12
#define DKK 64
#define PPOS (2*TSEQ-1)   // 1999
#define HALFW 50

// ---------------- positional encoding table ----------------
__global__ __launch_bounds__(256) void pos_enc_kernel(float* __restrict__ pe) {
    int idx = blockIdx.x * 256 + threadIdx.x;
    const int npair = PPOS * (CDIM / 2);
    if (idx >= npair) return;
    int j = idx / (CDIM / 2);
    int m = idx - j * (CDIM / 2);
    float rel = (float)(TSEQ - 1 - j);
    float div = expf(-(float)(2 * m) * (9.210340371976184f / (float)CDIM));
    float a = rel * div;
    pe[(size_t)j * CDIM + 2 * m]     = sinf(a);
    pe[(size_t)j * CDIM + 2 * m + 1] = cosf(a);
}

// ---------------- h = x * sqrt(C) ----------------
__global__ __launch_bounds__(256) void scale_kernel(const float* __restrict__ x,
                                                    float* __restrict__ h, int n) {
    int i = blockIdx.x * 256 + threadIdx.x;
    if (i < n) h[i] = x[i] * 27.712812921102035f;  // sqrt(768)
}

// ---------------- LayerNorm, one row (C=768) per block of 256 ----------------
__global__ __launch_bounds__(256) void ln_kernel(const float* __restrict__ x,
                                                 const float* __restrict__ g,
                                                 const float* __restrict__ bta,
                                                 float* __restrict__ y) {
    const int row = blockIdx.x, tid = threadIdx.x;
    const float* xr = x + (size_t)row * CDIM;
    float v0 = xr[tid], v1 = xr[tid + 256], v2 = xr[tid + 512];
    float s  = v0 + v1 + v2;
    float ss = v0 * v0 + v1 * v1 + v2 * v2;
#pragma unroll
    for (int off = 32; off; off >>= 1) {
        s  += __shfl_xor(s, off);
        ss += __shfl_xor(ss, off);
    }
    __shared__ float sm[4], sq[4];
    int wid = tid >> 6, lane = tid & 63;
    if (lane == 0) { sm[wid] = s; sq[wid] = ss; }
    __syncthreads();
    float st  = sm[0] + sm[1] + sm[2] + sm[3];
    float sst = sq[0] + sq[1] + sq[2] + sq[3];
    float mean = st * (1.f / CDIM);
    float var  = sst * (1.f / CDIM) - mean * mean;
    float rstd = rsqrtf(var + 1e-5f);
    float* yr = y + (size_t)row * CDIM;
    yr[tid]       = (v0 - mean) * rstd * g[tid]       + bta[tid];
    yr[tid + 256] = (v1 - mean) * rstd * g[tid + 256] + bta[tid + 256];
    yr[tid + 512] = (v2 - mean) * rstd * g[tid + 512] + bta[tid + 512];
}

// ---------------- GELU (tanh approx, matches jax.nn.gelu default) ----------------
__device__ __forceinline__ float gelu_f(float x) {
    float u = 0.7978845608028654f * (x + 0.044715f * x * x * x);
    return 0.5f * x * (1.f + tanhf(u));
}

// ---------------- f32 tiled GEMM: Out[M,768] = A[M,768] @ W[768,768] (+bias)(+epi)
// EPI: 0 = store, 1 = gelu(store), 2 = Out += acc+bias (residual accumulate)
template <int EPI>
__global__ __launch_bounds__(256) void gemm768(const float* __restrict__ A,
                                               const float* __restrict__ W,
                                               const float* __restrict__ bias,
                                               float* __restrict__ Out, int M) {
    __shared__ float As[16][68];
    __shared__ float Bs[16][68];
    const int tid = threadIdx.x;
    const int row0 = blockIdx.x * 64, col0 = blockIdx.y * 64;
    const int tx = tid & 15, ty = tid >> 4;
    const int ak = tid & 15, am = (tid >> 4) << 2;   // A: k = tid%16, 4 rows
    const int bk = tid >> 4, bn = (tid & 15) << 2;   // B: k = tid/16, 4 cols (float4)
    float acc[4][4] = {};
    for (int k0 = 0; k0 < CDIM; k0 += 16) {
#pragma unroll
        for (int i = 0; i < 4; ++i) {
            int m = row0 + am + i;
            As[ak][am + i] = (m < M) ? A[(size_t)m * CDIM + k0 + ak] : 0.f;
        }
        const float4 bv = *(const float4*)&W[(size_t)(k0 + bk) * CDIM + col0 + bn];
        *(float4*)&Bs[bk][bn] = bv;
        __syncthreads();
#pragma unroll
        for (int k = 0; k < 16; ++k) {
            float4 a4 = *(const float4*)&As[k][ty << 2];
            float4 b4 = *(const float4*)&Bs[k][tx << 2];
            float ar[4] = {a4.x, a4.y, a4.z, a4.w};
            float br[4] = {b4.x, b4.y, b4.z, b4.w};
#pragma unroll
            for (int i = 0; i < 4; ++i)
#pragma unroll
                for (int j = 0; j < 4; ++j)
                    acc[i][j] = fmaf(ar[i], br[j], acc[i][j]);
        }
        __syncthreads();
    }
    float4 bs4 = bias ? *(const float4*)&bias[col0 + (tx << 2)]
                      : make_float4(0.f, 0.f, 0.f, 0.f);
#pragma unroll
    for (int i = 0; i < 4; ++i) {
        int m = row0 + (ty << 2) + i;
        if (m >= M) continue;
        float r[4];
        r[0] = acc[i][0] + bs4.x; r[1] = acc[i][1] + bs4.y;
        r[2] = acc[i][2] + bs4.z; r[3] = acc[i][3] + bs4.w;
        float* op = &Out[(size_t)m * CDIM + col0 + (tx << 2)];
        if (EPI == 1) {
#pragma unroll
            for (int j = 0; j < 4; ++j) r[j] = gelu_f(r[j]);
        }
        if (EPI == 2) {
            float4 old = *(const float4*)op;
            r[0] += old.x; r[1] += old.y; r[2] += old.z; r[3] += old.w;
        }
        float4 rv = make_float4(r[0], r[1], r[2], r[3]);
        *(float4*)op = rv;
    }
}

// ---------------- banded rel-pos attention: one wave per (b, head, t) ----------------
// q,k,v: (B,T,H,DK) flat; p: (2T-1,H,DK); o: (B,T,H,DK)
__global__ __launch_bounds__(256) void attn_kernel(const float* __restrict__ q,
                                                   const float* __restrict__ k,
                                                   const float* __restrict__ v,
                                                   const float* __restrict__ p,
                                                   const float* __restrict__ pos_u,
                                                   const float* __restrict__ pos_v,
                                                   float* __restrict__ o) {
    int wid = (blockIdx.x << 2) | (threadIdx.x >> 6);
    if (wid >= BBATCH * HHEADS * TSEQ) return;
    const int lane = threadIdx.x & 63;
    const int t    = wid % TSEQ;
    const int bh   = wid / TSEQ;
    const int head = bh % HHEADS;
    const int b    = bh / HHEADS;

    const size_t qoff = ((size_t)b * TSEQ + t) * CDIM + head * DKK + lane;
    const float qraw = q[qoff];
    const float qu = qraw + pos_u[head * DKK + lane];
    const float qv = qraw + pos_v[head * DKK + lane];

    const int slo = (t > HALFW) ? t - HALFW : 0;
    const int shi = (t + HALFW < TSEQ) ? t + HALFW : TSEQ - 1;

    const float* kbase = k + (size_t)b * TSEQ * CDIM + head * DKK + lane;
    const float* pbase = p + (size_t)(TSEQ - 1 - t) * CDIM + head * DKK + lane;

    float sc0 = 0.f, sc1 = 0.f;     // scores for band index lane, lane+64
    float mx = -1e30f;
    for (int s = slo; s <= shi; ++s) {
        float kk = kbase[(size_t)s * CDIM];
        float pp = pbase[(size_t)s * CDIM];
        float part = qu * kk + qv * pp;
#pragma unroll
        for (int off = 32; off; off >>= 1) part += __shfl_xor(part, off);
        part *= 0.125f;  // 1/sqrt(64)
        int j = s - slo;
        sc0 = (j == lane)      ? part : sc0;
        sc1 = (j == lane + 64) ? part : sc1;
        mx = fmaxf(mx, part);
    }
    const int ns = shi - slo + 1;
    float e0 = (lane < ns)      ? __expf(sc0 - mx) : 0.f;
    float e1 = (lane + 64 < ns) ? __expf(sc1 - mx) : 0.f;
    float se = e0 + e1;
#pragma unroll
    for (int off = 32; off; off >>= 1) se += __shfl_xor(se, off);
    const float inv = 1.f / se;

    const float* vbase = v + (size_t)b * TSEQ * CDIM + head * DKK + lane;
    float acc = 0.f;
    for (int s = slo; s <= shi; ++s) {
        int j = s - slo;
        float w = __shfl((j < 64) ? e0 : e1, j & 63);
        acc = fmaf(w, vbase[(size_t)s * CDIM], acc);
    }
    o[qoff] = acc * inv;
}

// ---------------- launch ----------------
extern "C" void kernel_launch(void* const* d_in, const int* in_sizes, int n_in,
                              void* d_out, int out_size, void* d_ws, size_t ws_size,
                              hipStream_t stream) {
    const float* x     = (const float*)d_in[0];
    const float* Wq    = (const float*)d_in[1];
    const float* bq    = (const float*)d_in[2];
    const float* Wk    = (const float*)d_in[3];
    const float* bk    = (const float*)d_in[4];
    const float* Wv    = (const float*)d_in[5];
    const float* bv    = (const float*)d_in[6];
    const float* Wo    = (const float*)d_in[7];
    const float* bo    = (const float*)d_in[8];
    const float* Wp    = (const float*)d_in[9];
    const float* pos_u = (const float*)d_in[10];
    const float* pos_v = (const float*)d_in[11];
    const float* ln1g  = (const float*)d_in[12];
    const float* ln1b  = (const float*)d_in[13];
    const float* ln2g  = (const float*)d_in[14];
    const float* ln2b  = (const float*)d_in[15];
    const float* W1    = (const float*)d_in[16];
    const float* b1    = (const float*)d_in[17];
    const float* W2    = (const float*)d_in[18];
    const float* b2    = (const float*)d_in[19];
    // d_in[20] = att_mask: implied by the band structure, unused.

    float* h  = (float*)d_out;                  // h lives in d_out
    float* pe = (float*)d_ws;
    float* pb = pe + (size_t)PPOS * CDIM;
    float* y  = pb + (size_t)PPOS * CDIM;
    float* q  = y  + (size_t)BBATCH * TSEQ * CDIM;
    float* kk = q  + (size_t)BBATCH * TSEQ * CDIM;
    float* vv = kk + (size_t)BBATCH * TSEQ * CDIM;
    // o reuses y; FFN hidden reuses q.

    const int M = BBATCH * TSEQ;  // 4000
    pos_enc_kernel<<<(PPOS * (CDIM / 2) + 255) / 256, 256, 0, stream>>>(pe);
    scale_kernel<<<(M * CDIM + 255) / 256, 256, 0, stream>>>(x, h, M * CDIM);

    dim3 ggemm((M + 63) / 64, CDIM / 64);
    dim3 ggemmP((PPOS + 63) / 64, CDIM / 64);
    for (int l = 0; l < LNUM; ++l) {
        const size_t wo = (size_t)l * CDIM * CDIM;
        ln_kernel<<<M, 256, 0, stream>>>(h, ln1g + l * CDIM, ln1b + l * CDIM, y);
        gemm768<0><<<ggemm, 256, 0, stream>>>(y, Wq + wo, bq + l * CDIM, q, M);
        gemm768<0><<<ggemm, 256, 0, stream>>>(y, Wk + wo, bk + l * CDIM, kk, M);
        gemm768<0><<<ggemm, 256, 0, stream>>>(y, Wv + wo, bv + l * CDIM, vv, M);
        gemm768<0><<<ggemmP, 256, 0, stream>>>(pe, Wp + wo, nullptr, pb, PPOS);
        attn_kernel<<<(BBATCH * HHEADS * TSEQ) / 4, 256, 0, stream>>>(
            q, kk, vv, pb, pos_u + l * HHEADS * DKK, pos_v + l * HHEADS * DKK, y);
        gemm768<2><<<ggemm, 256, 0, stream>>>(y, Wo + wo, bo + l * CDIM, h, M);
        ln_kernel<<<M, 256, 0, stream>>>(h, ln2g + l * CDIM, ln2b + l * CDIM, y);
        gemm768<1><<<ggemm, 256, 0, stream>>>(y, W1 + wo, b1 + l * CDIM, q, M);
        gemm768<2><<<ggemm, 256, 0, stream>>>(q, W2 + wo, b2 + l * CDIM, h, M);
    }
}

// Round 2
// 1133.121 us; speedup vs baseline: 1.8485x; 1.8485x over previous
//
#include <hip/hip_runtime.h>
#include <math.h>

#define LNUM 2
#define BBATCH 4
#define TSEQ 1000
#define CDIM 768
#define HHEADS 12
#define DKK 64
#define PPOS (2*TSEQ-1)   // 1999
#define HALFW 50
#define MROWS (BBATCH*TSEQ)     // 4000
#define MPAD 4096
#define QKVDIM (3*CDIM)         // 2304

typedef __attribute__((ext_vector_type(8))) short s16x8;
typedef __attribute__((ext_vector_type(4))) float f32x4;

__device__ __forceinline__ ushort f2bf(float x) {
    unsigned u = __float_as_uint(x);
    unsigned r = u + 0x7FFFu + ((u >> 16) & 1u);
    return (ushort)(r >> 16);
}
__device__ __forceinline__ float bf2f(ushort h) {
    return __uint_as_float(((unsigned)h) << 16);
}
__device__ __forceinline__ float gelu_f(float x) {
    float u = 0.7978845608028654f * (x + 0.044715f * x * x * x);
    return 0.5f * x * (1.f + tanhf(u));
}
__device__ __forceinline__ void gload_lds16(const void* g, void* l) {
    __builtin_amdgcn_global_load_lds(
        (const __attribute__((address_space(1))) void*)g,
        (__attribute__((address_space(3))) void*)l, 16, 0, 0);
}

// ---------------- weight transpose + bf16 convert ----------------
// z = l*7 + m ; m: 0..2 -> Wq/Wk/Wv into Wtqkv, 3 -> Wp, 4 -> Wo, 5 -> W1, 6 -> W2
// dst[n*768 + k] = (bf16) src[k*768 + n]
__global__ __launch_bounds__(256) void transpose_pack(
    const float* __restrict__ Wq, const float* __restrict__ Wk,
    const float* __restrict__ Wv, const float* __restrict__ Wp,
    const float* __restrict__ Wo, const float* __restrict__ W1,
    const float* __restrict__ W2,
    ushort* __restrict__ Wtqkv, ushort* __restrict__ Wtp,
    ushort* __restrict__ Wto, ushort* __restrict__ Wt1, ushort* __restrict__ Wt2) {
    const int l = blockIdx.z / 7, m = blockIdx.z % 7;
    const float* srcs[7] = {Wq, Wk, Wv, Wp, Wo, W1, W2};
    const float* src = srcs[m] + (size_t)l * CDIM * CDIM;
    ushort* dst;
    if (m < 3)      dst = Wtqkv + (size_t)l * QKVDIM * CDIM + (size_t)m * CDIM * CDIM;
    else if (m == 3) dst = Wtp + (size_t)l * CDIM * CDIM;
    else if (m == 4) dst = Wto + (size_t)l * CDIM * CDIM;
    else if (m == 5) dst = Wt1 + (size_t)l * CDIM * CDIM;
    else             dst = Wt2 + (size_t)l * CDIM * CDIM;
    __shared__ float tile[32][33];
    const int tx = threadIdx.x, ty = threadIdx.y;       // (32, 8)
    const int c0 = blockIdx.x * 32, r0 = blockIdx.y * 32;
#pragma unroll
    for (int i = 0; i < 4; ++i)
        tile[ty + i * 8][tx] = src[(size_t)(r0 + ty + i * 8) * CDIM + c0 + tx];
    __syncthreads();
#pragma unroll
    for (int i = 0; i < 4; ++i)
        dst[(size_t)(c0 + ty + i * 8) * CDIM + r0 + tx] = f2bf(tile[tx][ty + i * 8]);
}

__global__ __launch_bounds__(256) void pack_bias(const float* __restrict__ bq,
                                                 const float* __restrict__ bk,
                                                 const float* __restrict__ bv,
                                                 float* __restrict__ bqkv) {
    int idx = blockIdx.x * 256 + threadIdx.x;
    if (idx >= LNUM * QKVDIM) return;
    int l = idx / QKVDIM, c = idx - l * QKVDIM;
    float v;
    if (c < CDIM)            v = bq[l * CDIM + c];
    else if (c < 2 * CDIM)   v = bk[l * CDIM + c - CDIM];
    else                     v = bv[l * CDIM + c - 2 * CDIM];
    bqkv[idx] = v;
}

// ---------------- positional encoding, only rows [896, 1152) are ever used ----------------
__global__ __launch_bounds__(256) void pos_enc_kernel(ushort* __restrict__ pe) {
    int idx = blockIdx.x * 256 + threadIdx.x;
    const int npair = 256 * (CDIM / 2);
    if (idx >= npair) return;
    int jloc = idx / (CDIM / 2);
    int m = idx - jloc * (CDIM / 2);
    int j = 896 + jloc;
    float rel = (float)(TSEQ - 1 - j);
    float div = expf(-(float)(2 * m) * (9.210340371976184f / (float)CDIM));
    float a = rel * div;
    pe[(size_t)j * CDIM + 2 * m]     = f2bf(sinf(a));
    pe[(size_t)j * CDIM + 2 * m + 1] = f2bf(cosf(a));
}

__global__ __launch_bounds__(256) void scale_kernel(const float* __restrict__ x,
                                                    float* __restrict__ h, int n) {
    int i = blockIdx.x * 256 + threadIdx.x;
    if (i < n) h[i] = x[i] * 27.712812921102035f;  // sqrt(768)
}

// ---------------- LayerNorm: f32 in, bf16 out ----------------
__global__ __launch_bounds__(256) void ln_kernel(const float* __restrict__ x,
                                                 const float* __restrict__ g,
                                                 const float* __restrict__ bta,
                                                 ushort* __restrict__ y) {
    const int row = blockIdx.x, tid = threadIdx.x;
    const float* xr = x + (size_t)row * CDIM;
    float v0 = xr[tid], v1 = xr[tid + 256], v2 = xr[tid + 512];
    float s  = v0 + v1 + v2;
    float ss = v0 * v0 + v1 * v1 + v2 * v2;
#pragma unroll
    for (int off = 32; off; off >>= 1) {
        s  += __shfl_xor(s, off);
        ss += __shfl_xor(ss, off);
    }
    __shared__ float sm[4], sq[4];
    int wid = tid >> 6, lane = tid & 63;
    if (lane == 0) { sm[wid] = s; sq[wid] = ss; }
    __syncthreads();
    float st  = sm[0] + sm[1] + sm[2] + sm[3];
    float sst = sq[0] + sq[1] + sq[2] + sq[3];
    float mean = st * (1.f / CDIM);
    float var  = sst * (1.f / CDIM) - mean * mean;
    float rstd = rsqrtf(var + 1e-5f);
    ushort* yr = y + (size_t)row * CDIM;
    yr[tid]       = f2bf((v0 - mean) * rstd * g[tid]       + bta[tid]);
    yr[tid + 256] = f2bf((v1 - mean) * rstd * g[tid + 256] + bta[tid + 256]);
    yr[tid + 512] = f2bf((v2 - mean) * rstd * g[tid + 512] + bta[tid + 512]);
}

// ---------------- MFMA bf16 GEMM: Out[M,N] = A[M,768] @ Bt[N,768]^T (+bias)(+epi)
// EPI: 0 = bf16 store, 1 = gelu -> bf16 store, 2 = f32 residual accumulate
template <int EPI>
__global__ __launch_bounds__(256) void gemm_mfma(const ushort* __restrict__ A,
                                                 const ushort* __restrict__ Bt,
                                                 const float* __restrict__ bias,
                                                 void* __restrict__ Out,
                                                 int M, int ldo) {
    __shared__ ushort lds[8192];          // [256 rows][32 k], rows 0-127 = A, 128-255 = B
    const int tid = threadIdx.x;
    const int w = tid >> 6, lane = tid & 63;
    const int row0 = blockIdx.x * 128, col0 = blockIdx.y * 128;
    const int subrow = lane >> 2;          // 0..15
    const int kchunk = (lane & 3) * 8;     // element offset within BK
    f32x4 acc[4][4] = {};
    for (int k0 = 0; k0 < CDIM; k0 += 32) {
        __syncthreads();
#pragma unroll
        for (int c = 0; c < 4; ++c) {
            const int r = (w & 1) * 64 + c * 16 + subrow;
            const ushort* src = (w < 2)
                ? A  + (size_t)(row0 + r) * CDIM + k0 + kchunk
                : Bt + (size_t)(col0 + r) * CDIM + k0 + kchunk;
            gload_lds16(src, (char*)lds + w * 4096 + c * 1024);
        }
        __syncthreads();
        const int wm = (w >> 1) * 64, wn = (w & 1) * 64;
        s16x8 af[4], bfr[4];
#pragma unroll
        for (int i = 0; i < 4; ++i)
            af[i] = *(const s16x8*)&lds[(wm + i * 16 + (lane & 15)) * 32 + (lane >> 4) * 8];
#pragma unroll
        for (int j = 0; j < 4; ++j)
            bfr[j] = *(const s16x8*)&lds[(128 + wn + j * 16 + (lane & 15)) * 32 + (lane >> 4) * 8];
#pragma unroll
        for (int i = 0; i < 4; ++i)
#pragma unroll
            for (int j = 0; j < 4; ++j)
                acc[i][j] = __builtin_amdgcn_mfma_f32_16x16x32_bf16(af[i], bfr[j], acc[i][j], 0, 0, 0);
    }
    const int crow0 = row0 + (w >> 1) * 64;
    const int ccol0 = col0 + (w & 1) * 64;
    const int lr = (lane >> 4) * 4;
    const int lc = lane & 15;
#pragma unroll
    for (int j = 0; j < 4; ++j) {
        const int col = ccol0 + j * 16 + lc;
        const float bv = bias ? bias[col] : 0.f;
#pragma unroll
        for (int i = 0; i < 4; ++i) {
#pragma unroll
            for (int r = 0; r < 4; ++r) {
                const int row = crow0 + i * 16 + lr + r;
                if (row >= M) continue;
                const float v = acc[i][j][r] + bv;
                if (EPI == 0)
                    ((ushort*)Out)[(size_t)row * ldo + col] = f2bf(v);
                else if (EPI == 1)
                    ((ushort*)Out)[(size_t)row * ldo + col] = f2bf(gelu_f(v));
                else {
                    float* p = (float*)Out + (size_t)row * ldo + col;
                    *p += v;
                }
            }
        }
    }
}

// ---------------- banded rel-pos attention, lane = key index ----------------
// qkv: (4000, 2304) bf16 [q|k|v]; pb: (2048, 768) bf16; o: (4000,768) bf16
__global__ __launch_bounds__(256) void attn_kernel(const ushort* __restrict__ qkv,
                                                   const ushort* __restrict__ pb,
                                                   const float* __restrict__ pos_u,
                                                   const float* __restrict__ pos_v,
                                                   ushort* __restrict__ o) {
    __shared__ float quv[4][2][64];
    __shared__ float wsm[4][128];
    const int ws = threadIdx.x >> 6, lane = threadIdx.x & 63;
    const int wid = blockIdx.x * 4 + ws;       // = (b*12 + h)*1000 + t
    const int t = wid % TSEQ;
    const int bh = wid / TSEQ;
    const int h = bh % HHEADS;
    const int b = bh / HHEADS;

    const size_t qoff = (size_t)(b * TSEQ + t) * QKVDIM + h * DKK;
    const float qraw = bf2f(qkv[qoff + lane]);
    quv[ws][0][lane] = qraw + pos_u[h * DKK + lane];
    quv[ws][1][lane] = qraw + pos_v[h * DKK + lane];
    __syncthreads();

    const int slo = (t > HALFW) ? t - HALFW : 0;
    const int shi = (t + HALFW < TSEQ) ? t + HALFW : TSEQ - 1;
    const int ns = shi - slo + 1;

    float sc[2] = {-1e30f, -1e30f};
#pragma unroll
    for (int sr = 0; sr < 2; ++sr) {
        if (sr == 1 && ns <= 64) break;          // wave-uniform
        const int sidx = slo + lane + sr * 64;
        const bool valid = sidx <= shi;
        const int srow = valid ? sidx : shi;
        const ushort* kp = qkv + (size_t)(b * TSEQ + srow) * QKVDIM + CDIM + h * DKK;
        const ushort* pp = pb + (size_t)(TSEQ - 1 - t + srow) * CDIM + h * DKK;
        float dot = 0.f;
#pragma unroll
        for (int c = 0; c < 8; ++c) {
            s16x8 kv8 = *(const s16x8*)(kp + c * 8);
            s16x8 pv8 = *(const s16x8*)(pp + c * 8);
#pragma unroll
            for (int e = 0; e < 8; ++e) {
                dot += quv[ws][0][c * 8 + e] * bf2f((ushort)kv8[e])
                     + quv[ws][1][c * 8 + e] * bf2f((ushort)pv8[e]);
            }
        }
        if (valid) sc[sr] = dot * 0.125f;
    }

    float mx = fmaxf(sc[0], sc[1]);
#pragma unroll
    for (int off = 32; off; off >>= 1) mx = fmaxf(mx, __shfl_xor(mx, off));
    float e0 = __expf(sc[0] - mx);
    float e1 = __expf(sc[1] - mx);
    float se = e0 + e1;
#pragma unroll
    for (int off = 32; off; off >>= 1) se += __shfl_xor(se, off);
    const float inv = 1.f / se;
    wsm[ws][lane]      = e0 * inv;
    wsm[ws][64 + lane] = e1 * inv;
    __syncthreads();

    const ushort* vbase = qkv + (size_t)(b * TSEQ + slo) * QKVDIM + 2 * CDIM + h * DKK + lane;
    float acc = 0.f;
    for (int j = 0; j < ns; ++j)
        acc = fmaf(wsm[ws][j], bf2f(vbase[(size_t)j * QKVDIM]), acc);
    o[(size_t)(b * TSEQ + t) * CDIM + h * DKK + lane] = f2bf(acc);
}

// ---------------- launch ----------------
extern "C" void kernel_launch(void* const* d_in, const int* in_sizes, int n_in,
                              void* d_out, int out_size, void* d_ws, size_t ws_size,
                              hipStream_t stream) {
    const float* x     = (const float*)d_in[0];
    const float* Wq    = (const float*)d_in[1];
    const float* bq    = (const float*)d_in[2];
    const float* Wk    = (const float*)d_in[3];
    const float* bk    = (const float*)d_in[4];
    const float* Wv    = (const float*)d_in[5];
    const float* bv    = (const float*)d_in[6];
    const float* Wo    = (const float*)d_in[7];
    const float* bo    = (const float*)d_in[8];
    const float* Wp    = (const float*)d_in[9];
    const float* pos_u = (const float*)d_in[10];
    const float* pos_v = (const float*)d_in[11];
    const float* ln1g  = (const float*)d_in[12];
    const float* ln1b  = (const float*)d_in[13];
    const float* ln2g  = (const float*)d_in[14];
    const float* ln2b  = (const float*)d_in[15];
    const float* W1    = (const float*)d_in[16];
    const float* b1    = (const float*)d_in[17];
    const float* W2    = (const float*)d_in[18];
    const float* b2    = (const float*)d_in[19];

    float* h = (float*)d_out;

    // workspace carve (bytes, all 256-aligned)
    char* p = (char*)d_ws;
    ushort* Wtqkv = (ushort*)p;               p += (size_t)LNUM * QKVDIM * CDIM * 2;
    ushort* Wtp   = (ushort*)p;               p += (size_t)LNUM * CDIM * CDIM * 2;
    ushort* Wto   = (ushort*)p;               p += (size_t)LNUM * CDIM * CDIM * 2;
    ushort* Wt1   = (ushort*)p;               p += (size_t)LNUM * CDIM * CDIM * 2;
    ushort* Wt2   = (ushort*)p;               p += (size_t)LNUM * CDIM * CDIM * 2;
    float*  bqkv  = (float*)p;                p += (size_t)LNUM * QKVDIM * 4;
    ushort* pe    = (ushort*)p;               p += (size_t)2048 * CDIM * 2;
    ushort* pb    = (ushort*)p;               p += (size_t)2048 * CDIM * 2;
    ushort* y     = (ushort*)p;               p += (size_t)MPAD * CDIM * 2;
    ushort* qkv   = (ushort*)p;               p += (size_t)MPAD * QKVDIM * 2;
    ushort* o     = (ushort*)p;               p += (size_t)MPAD * CDIM * 2;
    ushort* hid   = (ushort*)p;               p += (size_t)MPAD * CDIM * 2;

    // prep
    transpose_pack<<<dim3(24, 24, LNUM * 7), dim3(32, 8), 0, stream>>>(
        Wq, Wk, Wv, Wp, Wo, W1, W2, Wtqkv, Wtp, Wto, Wt1, Wt2);
    pack_bias<<<(LNUM * QKVDIM + 255) / 256, 256, 0, stream>>>(bq, bk, bv, bqkv);
    pos_enc_kernel<<<(256 * (CDIM / 2) + 255) / 256, 256, 0, stream>>>(pe);
    scale_kernel<<<(MROWS * CDIM + 255) / 256, 256, 0, stream>>>(x, h, MROWS * CDIM);

    const dim3 gQKV(32, QKVDIM / 128);    // (32, 18)
    const dim3 gC(32, CDIM / 128);        // (32, 6)
    const dim3 gP(2, CDIM / 128);         // rows 896..1151 of pe only
    for (int l = 0; l < LNUM; ++l) {
        const size_t wo = (size_t)l * CDIM * CDIM;
        ln_kernel<<<MROWS, 256, 0, stream>>>(h, ln1g + l * CDIM, ln1b + l * CDIM, y);
        gemm_mfma<0><<<gQKV, 256, 0, stream>>>(y, Wtqkv + (size_t)l * QKVDIM * CDIM,
                                               bqkv + l * QKVDIM, qkv, MROWS, QKVDIM);
        gemm_mfma<0><<<gP, 256, 0, stream>>>(pe + (size_t)896 * CDIM, Wtp + wo,
                                             nullptr, pb + (size_t)896 * CDIM, 256, CDIM);
        attn_kernel<<<(BBATCH * HHEADS * TSEQ) / 4, 256, 0, stream>>>(
            qkv, pb, pos_u + l * HHEADS * DKK, pos_v + l * HHEADS * DKK, o);
        gemm_mfma<2><<<gC, 256, 0, stream>>>(o, Wto + wo, bo + l * CDIM, h, MROWS, CDIM);
        ln_kernel<<<MROWS, 256, 0, stream>>>(h, ln2g + l * CDIM, ln2b + l * CDIM, y);
        gemm_mfma<1><<<gC, 256, 0, stream>>>(y, Wt1 + wo, b1 + l * CDIM, hid, MROWS, CDIM);
        gemm_mfma<2><<<gC, 256, 0, stream>>>(hid, Wt2 + wo, b2 + l * CDIM, h, MROWS, CDIM);
    }
}

// Round 3
// 393.130 us; speedup vs baseline: 5.3278x; 2.8823x over previous
//
#include <hip/hip_runtime.h>
#include <math.h>

#define LNUM 2
#define BBATCH 4
#define TSEQ 1000
#define CDIM 768
#define HHEADS 12
#define DKK 64
#define PPOS (2*TSEQ-1)   // 1999
#define HALFW 50
#define MROWS (BBATCH*TSEQ)     // 4000
#define MPAD 4096
#define QKVDIM (3*CDIM)         // 2304
#define NS 176                  // staged key span per 64-query tile

typedef __attribute__((ext_vector_type(8))) short s16x8;
typedef __attribute__((ext_vector_type(4))) float f32x4;

__device__ __forceinline__ ushort f2bf(float x) {
    unsigned u = __float_as_uint(x);
    unsigned r = u + 0x7FFFu + ((u >> 16) & 1u);
    return (ushort)(r >> 16);
}
__device__ __forceinline__ float bf2f(ushort h) {
    return __uint_as_float(((unsigned)h) << 16);
}
__device__ __forceinline__ float gelu_f(float x) {
    float u = 0.7978845608028654f * (x + 0.044715f * x * x * x);
    return 0.5f * x * (1.f + tanhf(u));
}
__device__ __forceinline__ void gload_lds16(const void* g, void* l) {
    __builtin_amdgcn_global_load_lds(
        (const __attribute__((address_space(1))) void*)g,
        (__attribute__((address_space(3))) void*)l, 16, 0, 0);
}

// ---------------- weight transpose + bf16 convert ----------------
__global__ __launch_bounds__(256) void transpose_pack(
    const float* __restrict__ Wq, const float* __restrict__ Wk,
    const float* __restrict__ Wv, const float* __restrict__ Wp,
    const float* __restrict__ Wo, const float* __restrict__ W1,
    const float* __restrict__ W2,
    ushort* __restrict__ Wtqkv, ushort* __restrict__ Wtp,
    ushort* __restrict__ Wto, ushort* __restrict__ Wt1, ushort* __restrict__ Wt2) {
    const int l = blockIdx.z / 7, m = blockIdx.z % 7;
    const float* srcs[7] = {Wq, Wk, Wv, Wp, Wo, W1, W2};
    const float* src = srcs[m] + (size_t)l * CDIM * CDIM;
    ushort* dst;
    if (m < 3)      dst = Wtqkv + (size_t)l * QKVDIM * CDIM + (size_t)m * CDIM * CDIM;
    else if (m == 3) dst = Wtp + (size_t)l * CDIM * CDIM;
    else if (m == 4) dst = Wto + (size_t)l * CDIM * CDIM;
    else if (m == 5) dst = Wt1 + (size_t)l * CDIM * CDIM;
    else             dst = Wt2 + (size_t)l * CDIM * CDIM;
    __shared__ float tile[32][33];
    const int tx = threadIdx.x, ty = threadIdx.y;       // (32, 8)
    const int c0 = blockIdx.x * 32, r0 = blockIdx.y * 32;
#pragma unroll
    for (int i = 0; i < 4; ++i)
        tile[ty + i * 8][tx] = src[(size_t)(r0 + ty + i * 8) * CDIM + c0 + tx];
    __syncthreads();
#pragma unroll
    for (int i = 0; i < 4; ++i)
        dst[(size_t)(c0 + ty + i * 8) * CDIM + r0 + tx] = f2bf(tile[tx][ty + i * 8]);
}

__global__ __launch_bounds__(256) void pack_bias(const float* __restrict__ bq,
                                                 const float* __restrict__ bk,
                                                 const float* __restrict__ bv,
                                                 float* __restrict__ bqkv) {
    int idx = blockIdx.x * 256 + threadIdx.x;
    if (idx >= LNUM * QKVDIM) return;
    int l = idx / QKVDIM, c = idx - l * QKVDIM;
    float v;
    if (c < CDIM)            v = bq[l * CDIM + c];
    else if (c < 2 * CDIM)   v = bk[l * CDIM + c - CDIM];
    else                     v = bv[l * CDIM + c - 2 * CDIM];
    bqkv[idx] = v;
}

// ---------------- positional encoding, only rows [896, 1152) are ever used ----------------
__global__ __launch_bounds__(256) void pos_enc_kernel(ushort* __restrict__ pe) {
    int idx = blockIdx.x * 256 + threadIdx.x;
    const int npair = 256 * (CDIM / 2);
    if (idx >= npair) return;
    int jloc = idx / (CDIM / 2);
    int m = idx - jloc * (CDIM / 2);
    int j = 896 + jloc;
    float rel = (float)(TSEQ - 1 - j);
    float div = expf(-(float)(2 * m) * (9.210340371976184f / (float)CDIM));
    float a = rel * div;
    pe[(size_t)j * CDIM + 2 * m]     = f2bf(sinf(a));
    pe[(size_t)j * CDIM + 2 * m + 1] = f2bf(cosf(a));
}

__global__ __launch_bounds__(256) void scale_kernel(const float* __restrict__ x,
                                                    float* __restrict__ h, int n) {
    int i = blockIdx.x * 256 + threadIdx.x;
    if (i < n) h[i] = x[i] * 27.712812921102035f;  // sqrt(768)
}

// ---------------- LayerNorm: f32 in, bf16 out ----------------
__global__ __launch_bounds__(256) void ln_kernel(const float* __restrict__ x,
                                                 const float* __restrict__ g,
                                                 const float* __restrict__ bta,
                                                 ushort* __restrict__ y) {
    const int row = blockIdx.x, tid = threadIdx.x;
    const float* xr = x + (size_t)row * CDIM;
    float v0 = xr[tid], v1 = xr[tid + 256], v2 = xr[tid + 512];
    float s  = v0 + v1 + v2;
    float ss = v0 * v0 + v1 * v1 + v2 * v2;
#pragma unroll
    for (int off = 32; off; off >>= 1) {
        s  += __shfl_xor(s, off);
        ss += __shfl_xor(ss, off);
    }
    __shared__ float sm[4], sq[4];
    int wid = tid >> 6, lane = tid & 63;
    if (lane == 0) { sm[wid] = s; sq[wid] = ss; }
    __syncthreads();
    float st  = sm[0] + sm[1] + sm[2] + sm[3];
    float sst = sq[0] + sq[1] + sq[2] + sq[3];
    float mean = st * (1.f / CDIM);
    float var  = sst * (1.f / CDIM) - mean * mean;
    float rstd = rsqrtf(var + 1e-5f);
    ushort* yr = y + (size_t)row * CDIM;
    yr[tid]       = f2bf((v0 - mean) * rstd * g[tid]       + bta[tid]);
    yr[tid + 256] = f2bf((v1 - mean) * rstd * g[tid + 256] + bta[tid + 256]);
    yr[tid + 512] = f2bf((v2 - mean) * rstd * g[tid + 512] + bta[tid + 512]);
}

// ---------------- MFMA bf16 GEMM (unchanged from round 2) ----------------
template <int EPI>
__global__ __launch_bounds__(256) void gemm_mfma(const ushort* __restrict__ A,
                                                 const ushort* __restrict__ Bt,
                                                 const float* __restrict__ bias,
                                                 void* __restrict__ Out,
                                                 int M, int ldo) {
    __shared__ ushort lds[8192];
    const int tid = threadIdx.x;
    const int w = tid >> 6, lane = tid & 63;
    const int row0 = blockIdx.x * 128, col0 = blockIdx.y * 128;
    const int subrow = lane >> 2;
    const int kchunk = (lane & 3) * 8;
    f32x4 acc[4][4] = {};
    for (int k0 = 0; k0 < CDIM; k0 += 32) {
        __syncthreads();
#pragma unroll
        for (int c = 0; c < 4; ++c) {
            const int r = (w & 1) * 64 + c * 16 + subrow;
            const ushort* src = (w < 2)
                ? A  + (size_t)(row0 + r) * CDIM + k0 + kchunk
                : Bt + (size_t)(col0 + r) * CDIM + k0 + kchunk;
            gload_lds16(src, (char*)lds + w * 4096 + c * 1024);
        }
        __syncthreads();
        const int wm = (w >> 1) * 64, wn = (w & 1) * 64;
        s16x8 af[4], bfr[4];
#pragma unroll
        for (int i = 0; i < 4; ++i)
            af[i] = *(const s16x8*)&lds[(wm + i * 16 + (lane & 15)) * 32 + (lane >> 4) * 8];
#pragma unroll
        for (int j = 0; j < 4; ++j)
            bfr[j] = *(const s16x8*)&lds[(128 + wn + j * 16 + (lane & 15)) * 32 + (lane >> 4) * 8];
#pragma unroll
        for (int i = 0; i < 4; ++i)
#pragma unroll
            for (int j = 0; j < 4; ++j)
                acc[i][j] = __builtin_amdgcn_mfma_f32_16x16x32_bf16(af[i], bfr[j], acc[i][j], 0, 0, 0);
    }
    const int crow0 = row0 + (w >> 1) * 64;
    const int ccol0 = col0 + (w & 1) * 64;
    const int lr = (lane >> 4) * 4;
    const int lc = lane & 15;
#pragma unroll
    for (int j = 0; j < 4; ++j) {
        const int col = ccol0 + j * 16 + lc;
        const float bv = bias ? bias[col] : 0.f;
#pragma unroll
        for (int i = 0; i < 4; ++i) {
#pragma unroll
            for (int r = 0; r < 4; ++r) {
                const int row = crow0 + i * 16 + lr + r;
                if (row >= M) continue;
                const float v = acc[i][j][r] + bv;
                if (EPI == 0)
                    ((ushort*)Out)[(size_t)row * ldo + col] = f2bf(v);
                else if (EPI == 1)
                    ((ushort*)Out)[(size_t)row * ldo + col] = f2bf(gelu_f(v));
                else {
                    float* p = (float*)Out + (size_t)row * ldo + col;
                    *p += v;
                }
            }
        }
    }
}

// ---------------- MFMA banded rel-pos attention ----------------
// Block = (b, h, 64-query tile). Keys [t0-50, t0+125] -> NS=176 staged rows.
// rel_shift identity: u = 50 - (t - s) = j - tloc, p row = 949 + u.
__global__ __launch_bounds__(256, 2) void attn_mfma(
    const ushort* __restrict__ qkv, const ushort* __restrict__ pb,
    const float* __restrict__ pos_u, const float* __restrict__ pos_v,
    ushort* __restrict__ o) {
    __shared__ __align__(16) char smem[75264];
    ushort* Qu = (ushort*)smem;                 // [64][72]
    ushort* Qv = (ushort*)(smem + 9216);        // [64][72]
    ushort* Kl = (ushort*)(smem + 18432);       // [176][72]
    ushort* Pp = (ushort*)(smem + 43776);       // [112][72]
    ushort* Bd = (ushort*)(smem + 59904);       // [4][16][120]
    ushort* Pl = (ushort*)smem;                 // phase2: [64][200]
    ushort* Vt = (ushort*)(smem + 25600);       // phase2: [64][200]

    const int tid = threadIdx.x;
    const int w = tid >> 6, lane = tid & 63;
    const int t0 = blockIdx.x * 64;
    const int h = blockIdx.y, b = blockIdx.z;

    // ---- stage Qu/Qv (one task per thread) ----
    {
        const int row = tid >> 2, c = (tid & 3) << 4;
        int t = t0 + row; t = (t < TSEQ) ? t : TSEQ - 1;
        const ushort* qp = qkv + (size_t)(b * TSEQ + t) * QKVDIM + h * DKK + c;
        const s16x8 a0 = *(const s16x8*)qp;
        const s16x8 a1 = *(const s16x8*)(qp + 8);
        const float* pu = pos_u + h * DKK + c;
        const float* pv = pos_v + h * DKK + c;
        s16x8 u0, u1, v0, v1;
#pragma unroll
        for (int e = 0; e < 8; ++e) {
            float q0 = bf2f((ushort)a0[e]), q1 = bf2f((ushort)a1[e]);
            u0[e] = (short)f2bf(q0 + pu[e]);  u1[e] = (short)f2bf(q1 + pu[8 + e]);
            v0[e] = (short)f2bf(q0 + pv[e]);  v1[e] = (short)f2bf(q1 + pv[8 + e]);
        }
        *(s16x8*)&Qu[row * 72 + c] = u0; *(s16x8*)&Qu[row * 72 + c + 8] = u1;
        *(s16x8*)&Qv[row * 72 + c] = v0; *(s16x8*)&Qv[row * 72 + c + 8] = v1;
    }
    // ---- stage K ----
    for (int task = tid; task < NS * 4; task += 256) {
        const int j = task >> 2, c = (task & 3) << 4;
        int kb = t0 - HALFW + j; kb = kb < 0 ? 0 : (kb < TSEQ ? kb : TSEQ - 1);
        const ushort* kp = qkv + (size_t)(b * TSEQ + kb) * QKVDIM + CDIM + h * DKK + c;
        *(s16x8*)&Kl[j * 72 + c]     = *(const s16x8*)kp;
        *(s16x8*)&Kl[j * 72 + c + 8] = *(const s16x8*)(kp + 8);
    }
    // ---- stage rel-pos rows 949..1060 ----
    for (int task = tid; task < 112 * 4; task += 256) {
        const int u = task >> 2, c = (task & 3) << 4;
        const ushort* pp = pb + (size_t)(949 + u) * CDIM + h * DKK + c;
        *(s16x8*)&Pp[u * 72 + c]     = *(const s16x8*)pp;
        *(s16x8*)&Pp[u * 72 + c + 8] = *(const s16x8*)(pp + 8);
    }
    __syncthreads();

    // ---- score MFMAs (wave w owns query rows m0..m0+15, all 176 key cols) ----
    const int m0 = w * 16;
    const int lr = lane & 15, lk = (lane >> 4) * 8;
    const f32x4 zero = {0.f, 0.f, 0.f, 0.f};
    s16x8 qu0 = *(const s16x8*)&Qu[(m0 + lr) * 72 + lk];
    s16x8 qu1 = *(const s16x8*)&Qu[(m0 + lr) * 72 + 32 + lk];
    s16x8 qv0 = *(const s16x8*)&Qv[(m0 + lr) * 72 + lk];
    s16x8 qv1 = *(const s16x8*)&Qv[(m0 + lr) * 72 + 32 + lk];
    f32x4 acS[11], acB[7];
#pragma unroll
    for (int jf = 0; jf < 11; ++jf) {
        s16x8 k0 = *(const s16x8*)&Kl[(jf * 16 + lr) * 72 + lk];
        s16x8 k1 = *(const s16x8*)&Kl[(jf * 16 + lr) * 72 + 32 + lk];
        acS[jf] = __builtin_amdgcn_mfma_f32_16x16x32_bf16(qu0, k0, zero, 0, 0, 0);
        acS[jf] = __builtin_amdgcn_mfma_f32_16x16x32_bf16(qu1, k1, acS[jf], 0, 0, 0);
    }
#pragma unroll
    for (int uf = 0; uf < 7; ++uf) {
        s16x8 p0 = *(const s16x8*)&Pp[(uf * 16 + lr) * 72 + lk];
        s16x8 p1 = *(const s16x8*)&Pp[(uf * 16 + lr) * 72 + 32 + lk];
        acB[uf] = __builtin_amdgcn_mfma_f32_16x16x32_bf16(qv0, p0, zero, 0, 0, 0);
        acB[uf] = __builtin_amdgcn_mfma_f32_16x16x32_bf16(qv1, p1, acB[uf], 0, 0, 0);
    }
    // ---- bd accumulator -> LDS (own-wave region) ----
    ushort* bdw = Bd + w * 16 * 120;
#pragma unroll
    for (int uf = 0; uf < 7; ++uf)
#pragma unroll
        for (int r = 0; r < 4; ++r)
            bdw[((lane >> 4) * 4 + r) * 120 + uf * 16 + lr] = f2bf(acB[uf][r]);
    // ---- combine + masked softmax (deferred 1/sum) ----
    float mx[4] = {-1e30f, -1e30f, -1e30f, -1e30f};
#pragma unroll
    for (int jf = 0; jf < 11; ++jf)
#pragma unroll
        for (int r = 0; r < 4; ++r) {
            const int tl = (lane >> 4) * 4 + r;
            const int tloc = m0 + tl;
            const int j = jf * 16 + lr;
            const int u = j - tloc;
            const int s = t0 - HALFW + j;
            const bool valid = (u >= 0) & (u <= 2 * HALFW) & (s >= 0) & (s < TSEQ)
                               & (t0 + tloc < TSEQ);
            float sc = -1e30f;
            if (valid) sc = (acS[jf][r] + bf2f(bdw[tl * 120 + u])) * 0.125f;
            acS[jf][r] = sc;
            mx[r] = fmaxf(mx[r], sc);
        }
#pragma unroll
    for (int r = 0; r < 4; ++r)
#pragma unroll
        for (int off = 8; off; off >>= 1)
            mx[r] = fmaxf(mx[r], __shfl_xor(mx[r], off));
    float sm[4] = {0.f, 0.f, 0.f, 0.f};
#pragma unroll
    for (int jf = 0; jf < 11; ++jf)
#pragma unroll
        for (int r = 0; r < 4; ++r) {
            float e = __expf(acS[jf][r] - mx[r]);
            acS[jf][r] = e;
            sm[r] += e;
        }
#pragma unroll
    for (int r = 0; r < 4; ++r) {
#pragma unroll
        for (int off = 8; off; off >>= 1) sm[r] += __shfl_xor(sm[r], off);
        sm[r] = 1.f / sm[r];
    }
    __syncthreads();   // all waves done reading Qu/Qv/Kl/Pp

    // ---- write P (bf16, A-frag layout) + zero pad cols 176..191 ----
#pragma unroll
    for (int jf = 0; jf < 11; ++jf)
#pragma unroll
        for (int r = 0; r < 4; ++r)
            Pl[(m0 + (lane >> 4) * 4 + r) * 200 + jf * 16 + lr] = f2bf(acS[jf][r]);
#pragma unroll
    for (int r = 0; r < 4; ++r)
        Pl[(m0 + (lane >> 4) * 4 + r) * 200 + 176 + lr] = 0;
    // ---- stage V transposed: Vt[d][j] (+ zero pad cols) ----
    for (int task = tid; task < 192 * 4; task += 256) {
        const int j = task >> 2, c = (task & 3) << 4;
        if (j < NS) {
            int kb = t0 - HALFW + j; kb = kb < 0 ? 0 : (kb < TSEQ ? kb : TSEQ - 1);
            const ushort* vp = qkv + (size_t)(b * TSEQ + kb) * QKVDIM + 2 * CDIM + h * DKK + c;
            const s16x8 v0 = *(const s16x8*)vp;
            const s16x8 v1 = *(const s16x8*)(vp + 8);
#pragma unroll
            for (int e = 0; e < 8; ++e) {
                Vt[(c + e) * 200 + j]     = (ushort)v0[e];
                Vt[(c + 8 + e) * 200 + j] = (ushort)v1[e];
            }
        } else {
#pragma unroll
            for (int e = 0; e < 16; ++e) Vt[(c + e) * 200 + j] = 0;
        }
    }
    __syncthreads();

    // ---- PV: O[16][64] = P[16][192] * Vt[64][192]^T ----
    f32x4 acO[4] = {};
#pragma unroll
    for (int ks = 0; ks < 6; ++ks) {
        s16x8 pa = *(const s16x8*)&Pl[(m0 + lr) * 200 + ks * 32 + lk];
#pragma unroll
        for (int nf = 0; nf < 4; ++nf) {
            s16x8 vb = *(const s16x8*)&Vt[(nf * 16 + lr) * 200 + ks * 32 + lk];
            acO[nf] = __builtin_amdgcn_mfma_f32_16x16x32_bf16(pa, vb, acO[nf], 0, 0, 0);
        }
    }
#pragma unroll
    for (int nf = 0; nf < 4; ++nf)
#pragma unroll
        for (int r = 0; r < 4; ++r) {
            const int t = t0 + m0 + (lane >> 4) * 4 + r;
            if (t < TSEQ)
                o[(size_t)(b * TSEQ + t) * CDIM + h * DKK + nf * 16 + lr] =
                    f2bf(acO[nf][r] * sm[r]);
        }
}

// ---------------- launch ----------------
extern "C" void kernel_launch(void* const* d_in, const int* in_sizes, int n_in,
                              void* d_out, int out_size, void* d_ws, size_t ws_size,
                              hipStream_t stream) {
    const float* x     = (const float*)d_in[0];
    const float* Wq    = (const float*)d_in[1];
    const float* bq    = (const float*)d_in[2];
    const float* Wk    = (const float*)d_in[3];
    const float* bk    = (const float*)d_in[4];
    const float* Wv    = (const float*)d_in[5];
    const float* bv    = (const float*)d_in[6];
    const float* Wo    = (const float*)d_in[7];
    const float* bo    = (const float*)d_in[8];
    const float* Wp    = (const float*)d_in[9];
    const float* pos_u = (const float*)d_in[10];
    const float* pos_v = (const float*)d_in[11];
    const float* ln1g  = (const float*)d_in[12];
    const float* ln1b  = (const float*)d_in[13];
    const float* ln2g  = (const float*)d_in[14];
    const float* ln2b  = (const float*)d_in[15];
    const float* W1    = (const float*)d_in[16];
    const float* b1    = (const float*)d_in[17];
    const float* W2    = (const float*)d_in[18];
    const float* b2    = (const float*)d_in[19];

    float* h = (float*)d_out;

    char* p = (char*)d_ws;
    ushort* Wtqkv = (ushort*)p;               p += (size_t)LNUM * QKVDIM * CDIM * 2;
    ushort* Wtp   = (ushort*)p;               p += (size_t)LNUM * CDIM * CDIM * 2;
    ushort* Wto   = (ushort*)p;               p += (size_t)LNUM * CDIM * CDIM * 2;
    ushort* Wt1   = (ushort*)p;               p += (size_t)LNUM * CDIM * CDIM * 2;
    ushort* Wt2   = (ushort*)p;               p += (size_t)LNUM * CDIM * CDIM * 2;
    float*  bqkv  = (float*)p;                p += (size_t)LNUM * QKVDIM * 4;
    ushort* pe    = (ushort*)p;               p += (size_t)2048 * CDIM * 2;
    ushort* pb    = (ushort*)p;               p += (size_t)2048 * CDIM * 2;
    ushort* y     = (ushort*)p;               p += (size_t)MPAD * CDIM * 2;
    ushort* qkv   = (ushort*)p;               p += (size_t)MPAD * QKVDIM * 2;
    ushort* o     = (ushort*)p;               p += (size_t)MPAD * CDIM * 2;
    ushort* hid   = (ushort*)p;               p += (size_t)MPAD * CDIM * 2;

    transpose_pack<<<dim3(24, 24, LNUM * 7), dim3(32, 8), 0, stream>>>(
        Wq, Wk, Wv, Wp, Wo, W1, W2, Wtqkv, Wtp, Wto, Wt1, Wt2);
    pack_bias<<<(LNUM * QKVDIM + 255) / 256, 256, 0, stream>>>(bq, bk, bv, bqkv);
    pos_enc_kernel<<<(256 * (CDIM / 2) + 255) / 256, 256, 0, stream>>>(pe);
    scale_kernel<<<(MROWS * CDIM + 255) / 256, 256, 0, stream>>>(x, h, MROWS * CDIM);

    const dim3 gQKV(32, QKVDIM / 128);
    const dim3 gC(32, CDIM / 128);
    const dim3 gP(2, CDIM / 128);
    const dim3 gA(16, HHEADS, BBATCH);
    for (int l = 0; l < LNUM; ++l) {
        const size_t wo = (size_t)l * CDIM * CDIM;
        ln_kernel<<<MROWS, 256, 0, stream>>>(h, ln1g + l * CDIM, ln1b + l * CDIM, y);
        gemm_mfma<0><<<gQKV, 256, 0, stream>>>(y, Wtqkv + (size_t)l * QKVDIM * CDIM,
                                               bqkv + l * QKVDIM, qkv, MROWS, QKVDIM);
        gemm_mfma<0><<<gP, 256, 0, stream>>>(pe + (size_t)896 * CDIM, Wtp + wo,
                                             nullptr, pb + (size_t)896 * CDIM, 256, CDIM);
        attn_mfma<<<gA, 256, 0, stream>>>(
            qkv, pb, pos_u + l * HHEADS * DKK, pos_v + l * HHEADS * DKK, o);
        gemm_mfma<2><<<gC, 256, 0, stream>>>(o, Wto + wo, bo + l * CDIM, h, MROWS, CDIM);
        ln_kernel<<<MROWS, 256, 0, stream>>>(h, ln2g + l * CDIM, ln2b + l * CDIM, y);
        gemm_mfma<1><<<gC, 256, 0, stream>>>(y, Wt1 + wo, b1 + l * CDIM, hid, MROWS, CDIM);
        gemm_mfma<2><<<gC, 256, 0, stream>>>(hid, Wt2 + wo, b2 + l * CDIM, h, MROWS, CDIM);
    }
}

// Round 4
// 383.967 us; speedup vs baseline: 5.4550x; 1.0239x over previous
//
#include <hip/hip_runtime.h>
#include <math.h>

#define LNUM 2
#define BBATCH 4
#define TSEQ 1000
#define CDIM 768
#define HHEADS 12
#define DKK 64
#define PPOS (2*TSEQ-1)   // 1999
#define HALFW 50
#define MROWS (BBATCH*TSEQ)     // 4000
#define MPAD 4096
#define QKVDIM (3*CDIM)         // 2304
#define NS 176                  // real key span per 64-query tile (padded to 192)

typedef __attribute__((ext_vector_type(8))) short s16x8;
typedef __attribute__((ext_vector_type(4))) short s16x4;
typedef __attribute__((ext_vector_type(4))) float f32x4;

#define LDSOFF(p) ((unsigned)(uintptr_t)(__attribute__((address_space(3))) const void*)(p))

__device__ __forceinline__ ushort f2bf(float x) {
    unsigned u = __float_as_uint(x);
    unsigned r = u + 0x7FFFu + ((u >> 16) & 1u);
    return (ushort)(r >> 16);
}
__device__ __forceinline__ float bf2f(ushort h) {
    return __uint_as_float(((unsigned)h) << 16);
}
__device__ __forceinline__ float gelu_f(float x) {
    float u = 0.7978845608028654f * (x + 0.044715f * x * x * x);
    return 0.5f * x * (1.f + tanhf(u));
}
__device__ __forceinline__ void gload_lds16(const void* g, void* l) {
    __builtin_amdgcn_global_load_lds(
        (const __attribute__((address_space(1))) void*)g,
        (__attribute__((address_space(3))) void*)l, 16, 0, 0);
}
__device__ __forceinline__ s16x4 tr_read(unsigned addr) {
    s16x4 d;
    asm volatile("ds_read_b64_tr_b16 %0, %1" : "=v"(d) : "v"(addr));
    return d;
}
__device__ __forceinline__ s16x4 tr_read128(unsigned addr) {
    s16x4 d;
    asm volatile("ds_read_b64_tr_b16 %0, %1 offset:128" : "=v"(d) : "v"(addr));
    return d;
}

// ---------------- weight transpose + bf16 convert ----------------
__global__ __launch_bounds__(256) void transpose_pack(
    const float* __restrict__ Wq, const float* __restrict__ Wk,
    const float* __restrict__ Wv, const float* __restrict__ Wp,
    const float* __restrict__ Wo, const float* __restrict__ W1,
    const float* __restrict__ W2,
    ushort* __restrict__ Wtqkv, ushort* __restrict__ Wtp,
    ushort* __restrict__ Wto, ushort* __restrict__ Wt1, ushort* __restrict__ Wt2) {
    const int l = blockIdx.z / 7, m = blockIdx.z % 7;
    const float* srcs[7] = {Wq, Wk, Wv, Wp, Wo, W1, W2};
    const float* src = srcs[m] + (size_t)l * CDIM * CDIM;
    ushort* dst;
    if (m < 3)       dst = Wtqkv + (size_t)l * QKVDIM * CDIM + (size_t)m * CDIM * CDIM;
    else if (m == 3) dst = Wtp + (size_t)l * CDIM * CDIM;
    else if (m == 4) dst = Wto + (size_t)l * CDIM * CDIM;
    else if (m == 5) dst = Wt1 + (size_t)l * CDIM * CDIM;
    else             dst = Wt2 + (size_t)l * CDIM * CDIM;
    __shared__ float tile[32][33];
    const int tx = threadIdx.x, ty = threadIdx.y;       // (32, 8)
    const int c0 = blockIdx.x * 32, r0 = blockIdx.y * 32;
#pragma unroll
    for (int i = 0; i < 4; ++i)
        tile[ty + i * 8][tx] = src[(size_t)(r0 + ty + i * 8) * CDIM + c0 + tx];
    __syncthreads();
#pragma unroll
    for (int i = 0; i < 4; ++i)
        dst[(size_t)(c0 + ty + i * 8) * CDIM + r0 + tx] = f2bf(tile[tx][ty + i * 8]);
}

// ---------------- fused small prep: pos-enc rows [896,1152) + qkv bias pack ----------------
__global__ __launch_bounds__(256) void prep_small(ushort* __restrict__ pe,
                                                  const float* __restrict__ bq,
                                                  const float* __restrict__ bk,
                                                  const float* __restrict__ bv,
                                                  float* __restrict__ bqkv) {
    int idx = blockIdx.x * 256 + threadIdx.x;
    const int npair = 256 * (CDIM / 2);
    if (idx < npair) {
        int jloc = idx / (CDIM / 2);
        int m = idx - jloc * (CDIM / 2);
        int j = 896 + jloc;
        float rel = (float)(TSEQ - 1 - j);
        float div = expf(-(float)(2 * m) * (9.210340371976184f / (float)CDIM));
        float a = rel * div;
        pe[(size_t)j * CDIM + 2 * m]     = f2bf(sinf(a));
        pe[(size_t)j * CDIM + 2 * m + 1] = f2bf(cosf(a));
    }
    if (idx < LNUM * QKVDIM) {
        int l = idx / QKVDIM, c = idx - l * QKVDIM;
        float v;
        if (c < CDIM)            v = bq[l * CDIM + c];
        else if (c < 2 * CDIM)   v = bk[l * CDIM + c - CDIM];
        else                     v = bv[l * CDIM + c - 2 * CDIM];
        bqkv[idx] = v;
    }
}

// ---------------- LayerNorm: f32 in (xscale-on-load), bf16 out; 192 thr, float4 ----------------
__global__ __launch_bounds__(192) void ln_kernel(const float* __restrict__ in,
                                                 const float* __restrict__ g,
                                                 const float* __restrict__ bta,
                                                 ushort* __restrict__ y, float xscale) {
    const int row = blockIdx.x, tid = threadIdx.x;
    float4 v = *(const float4*)&in[(size_t)row * CDIM + tid * 4];
    v.x *= xscale; v.y *= xscale; v.z *= xscale; v.w *= xscale;
    float s  = v.x + v.y + v.z + v.w;
    float ss = v.x * v.x + v.y * v.y + v.z * v.z + v.w * v.w;
#pragma unroll
    for (int off = 32; off; off >>= 1) {
        s  += __shfl_xor(s, off);
        ss += __shfl_xor(ss, off);
    }
    __shared__ float sm[3], sq[3];
    const int wid = tid >> 6, lane = tid & 63;
    if (lane == 0) { sm[wid] = s; sq[wid] = ss; }
    __syncthreads();
    const float st  = sm[0] + sm[1] + sm[2];
    const float sst = sq[0] + sq[1] + sq[2];
    const float mean = st * (1.f / CDIM);
    const float var  = sst * (1.f / CDIM) - mean * mean;
    const float rstd = rsqrtf(var + 1e-5f);
    const float4 g4 = *(const float4*)&g[tid * 4];
    const float4 b4 = *(const float4*)&bta[tid * 4];
    ushort o0 = f2bf((v.x - mean) * rstd * g4.x + b4.x);
    ushort o1 = f2bf((v.y - mean) * rstd * g4.y + b4.y);
    ushort o2 = f2bf((v.z - mean) * rstd * g4.z + b4.z);
    ushort o3 = f2bf((v.w - mean) * rstd * g4.w + b4.w);
    uint2 pk; pk.x = (unsigned)o0 | ((unsigned)o1 << 16);
    pk.y = (unsigned)o2 | ((unsigned)o3 << 16);
    *(uint2*)&y[(size_t)row * CDIM + tid * 4] = pk;
}

// ---------------- MFMA bf16 GEMM ----------------
// EPI 0: bf16 store; 1: gelu->bf16 store; 2: Out(f32) = resid*rscale + acc + bias
template <int EPI>
__global__ __launch_bounds__(256) void gemm_mfma(const ushort* __restrict__ A,
                                                 const ushort* __restrict__ Bt,
                                                 const float* __restrict__ bias,
                                                 void* Out, int M, int ldo,
                                                 const float* resid, float rscale) {
    __shared__ ushort lds[8192];
    const int tid = threadIdx.x;
    const int w = tid >> 6, lane = tid & 63;
    const int row0 = blockIdx.x * 128, col0 = blockIdx.y * 128;
    const int subrow = lane >> 2;
    const int kchunk = (lane & 3) * 8;
    f32x4 acc[4][4] = {};
    for (int k0 = 0; k0 < CDIM; k0 += 32) {
        __syncthreads();
#pragma unroll
        for (int c = 0; c < 4; ++c) {
            const int r = (w & 1) * 64 + c * 16 + subrow;
            const ushort* src = (w < 2)
                ? A  + (size_t)(row0 + r) * CDIM + k0 + kchunk
                : Bt + (size_t)(col0 + r) * CDIM + k0 + kchunk;
            gload_lds16(src, (char*)lds + w * 4096 + c * 1024);
        }
        __syncthreads();
        const int wm = (w >> 1) * 64, wn = (w & 1) * 64;
        s16x8 af[4], bfr[4];
#pragma unroll
        for (int i = 0; i < 4; ++i)
            af[i] = *(const s16x8*)&lds[(wm + i * 16 + (lane & 15)) * 32 + (lane >> 4) * 8];
#pragma unroll
        for (int j = 0; j < 4; ++j)
            bfr[j] = *(const s16x8*)&lds[(128 + wn + j * 16 + (lane & 15)) * 32 + (lane >> 4) * 8];
#pragma unroll
        for (int i = 0; i < 4; ++i)
#pragma unroll
            for (int j = 0; j < 4; ++j)
                acc[i][j] = __builtin_amdgcn_mfma_f32_16x16x32_bf16(af[i], bfr[j], acc[i][j], 0, 0, 0);
    }
    const int crow0 = row0 + (w >> 1) * 64;
    const int ccol0 = col0 + (w & 1) * 64;
    const int lr = (lane >> 4) * 4;
    const int lc = lane & 15;
#pragma unroll
    for (int j = 0; j < 4; ++j) {
        const int col = ccol0 + j * 16 + lc;
        const float bv = bias ? bias[col] : 0.f;
#pragma unroll
        for (int i = 0; i < 4; ++i) {
#pragma unroll
            for (int r = 0; r < 4; ++r) {
                const int row = crow0 + i * 16 + lr + r;
                if (row >= M) continue;
                const float v = acc[i][j][r] + bv;
                if (EPI == 0)
                    ((ushort*)Out)[(size_t)row * ldo + col] = f2bf(v);
                else if (EPI == 1)
                    ((ushort*)Out)[(size_t)row * ldo + col] = f2bf(gelu_f(v));
                else {
                    float* p = (float*)Out + (size_t)row * ldo + col;
                    *p = resid[(size_t)row * ldo + col] * rscale + v;
                }
            }
        }
    }
}

// ---------------- MFMA banded rel-pos attention ----------------
// Block = (b, h, 64-query tile). Keys [t0-50, t0+125] -> 176 cols (+16 zero-P pad).
// rel_shift identity: u = j - tloc, p row = 949 + u.
__global__ __launch_bounds__(256, 2) void attn_mfma(
    const ushort* __restrict__ qkv, const ushort* __restrict__ pb,
    const float* __restrict__ pos_u, const float* __restrict__ pos_v,
    ushort* __restrict__ o) {
    __shared__ __align__(16) char smem[75264];
    ushort* Qu = (ushort*)smem;                 // [64][72]
    ushort* Qv = (ushort*)(smem + 9216);        // [64][72]
    ushort* Kl = (ushort*)(smem + 18432);       // [176][72]
    ushort* Pp = (ushort*)(smem + 43776);       // [112][72]
    ushort* Bd = (ushort*)(smem + 59904);       // [4][16][120]
    ushort* Pl = (ushort*)smem;                 // phase2: [64][200]
    ushort* Vsub = (ushort*)(smem + 25600);     // phase2: [4 d0][192 j][16 d]

    const int tid = threadIdx.x;
    const int w = tid >> 6, lane = tid & 63;
    const int t0 = blockIdx.x * 64;
    const int h = blockIdx.y, b = blockIdx.z;

    // ---- stage Qu/Qv ----
    {
        const int row = tid >> 2, c = (tid & 3) << 4;
        int t = t0 + row; t = (t < TSEQ) ? t : TSEQ - 1;
        const ushort* qp = qkv + (size_t)(b * TSEQ + t) * QKVDIM + h * DKK + c;
        const s16x8 a0 = *(const s16x8*)qp;
        const s16x8 a1 = *(const s16x8*)(qp + 8);
        const float* pu = pos_u + h * DKK + c;
        const float* pv = pos_v + h * DKK + c;
        s16x8 u0, u1, v0, v1;
#pragma unroll
        for (int e = 0; e < 8; ++e) {
            float q0 = bf2f((ushort)a0[e]), q1 = bf2f((ushort)a1[e]);
            u0[e] = (short)f2bf(q0 + pu[e]);  u1[e] = (short)f2bf(q1 + pu[8 + e]);
            v0[e] = (short)f2bf(q0 + pv[e]);  v1[e] = (short)f2bf(q1 + pv[8 + e]);
        }
        *(s16x8*)&Qu[row * 72 + c] = u0; *(s16x8*)&Qu[row * 72 + c + 8] = u1;
        *(s16x8*)&Qv[row * 72 + c] = v0; *(s16x8*)&Qv[row * 72 + c + 8] = v1;
    }
    // ---- stage K ----
    for (int task = tid; task < NS * 4; task += 256) {
        const int j = task >> 2, c = (task & 3) << 4;
        int kb = t0 - HALFW + j; kb = kb < 0 ? 0 : (kb < TSEQ ? kb : TSEQ - 1);
        const ushort* kp = qkv + (size_t)(b * TSEQ + kb) * QKVDIM + CDIM + h * DKK + c;
        *(s16x8*)&Kl[j * 72 + c]     = *(const s16x8*)kp;
        *(s16x8*)&Kl[j * 72 + c + 8] = *(const s16x8*)(kp + 8);
    }
    // ---- stage rel-pos rows 949..1060 ----
    for (int task = tid; task < 112 * 4; task += 256) {
        const int u = task >> 2, c = (task & 3) << 4;
        const ushort* pp = pb + (size_t)(949 + u) * CDIM + h * DKK + c;
        *(s16x8*)&Pp[u * 72 + c]     = *(const s16x8*)pp;
        *(s16x8*)&Pp[u * 72 + c + 8] = *(const s16x8*)(pp + 8);
    }
    __syncthreads();

    // ---- score MFMAs ----
    const int m0 = w * 16;
    const int lr = lane & 15, lk = (lane >> 4) * 8;
    const f32x4 zero = {0.f, 0.f, 0.f, 0.f};
    s16x8 qu0 = *(const s16x8*)&Qu[(m0 + lr) * 72 + lk];
    s16x8 qu1 = *(const s16x8*)&Qu[(m0 + lr) * 72 + 32 + lk];
    s16x8 qv0 = *(const s16x8*)&Qv[(m0 + lr) * 72 + lk];
    s16x8 qv1 = *(const s16x8*)&Qv[(m0 + lr) * 72 + 32 + lk];
    f32x4 acS[11], acB[7];
#pragma unroll
    for (int jf = 0; jf < 11; ++jf) {
        s16x8 k0 = *(const s16x8*)&Kl[(jf * 16 + lr) * 72 + lk];
        s16x8 k1 = *(const s16x8*)&Kl[(jf * 16 + lr) * 72 + 32 + lk];
        acS[jf] = __builtin_amdgcn_mfma_f32_16x16x32_bf16(qu0, k0, zero, 0, 0, 0);
        acS[jf] = __builtin_amdgcn_mfma_f32_16x16x32_bf16(qu1, k1, acS[jf], 0, 0, 0);
    }
#pragma unroll
    for (int uf = 0; uf < 7; ++uf) {
        s16x8 p0 = *(const s16x8*)&Pp[(uf * 16 + lr) * 72 + lk];
        s16x8 p1 = *(const s16x8*)&Pp[(uf * 16 + lr) * 72 + 32 + lk];
        acB[uf] = __builtin_amdgcn_mfma_f32_16x16x32_bf16(qv0, p0, zero, 0, 0, 0);
        acB[uf] = __builtin_amdgcn_mfma_f32_16x16x32_bf16(qv1, p1, acB[uf], 0, 0, 0);
    }
    // ---- bd -> LDS (own-wave region) ----
    ushort* bdw = Bd + w * 16 * 120;
#pragma unroll
    for (int uf = 0; uf < 7; ++uf)
#pragma unroll
        for (int r = 0; r < 4; ++r)
            bdw[((lane >> 4) * 4 + r) * 120 + uf * 16 + lr] = f2bf(acB[uf][r]);
    // ---- combine + masked softmax (deferred 1/sum) ----
    float mx[4] = {-1e30f, -1e30f, -1e30f, -1e30f};
#pragma unroll
    for (int jf = 0; jf < 11; ++jf)
#pragma unroll
        for (int r = 0; r < 4; ++r) {
            const int tl = (lane >> 4) * 4 + r;
            const int tloc = m0 + tl;
            const int j = jf * 16 + lr;
            const int u = j - tloc;
            const int s = t0 - HALFW + j;
            const bool valid = (u >= 0) & (u <= 2 * HALFW) & (s >= 0) & (s < TSEQ)
                               & (t0 + tloc < TSEQ);
            float sc = -1e30f;
            if (valid) sc = (acS[jf][r] + bf2f(bdw[tl * 120 + u])) * 0.125f;
            acS[jf][r] = sc;
            mx[r] = fmaxf(mx[r], sc);
        }
#pragma unroll
    for (int r = 0; r < 4; ++r)
#pragma unroll
        for (int off = 8; off; off >>= 1)
            mx[r] = fmaxf(mx[r], __shfl_xor(mx[r], off));
    float sm[4] = {0.f, 0.f, 0.f, 0.f};
#pragma unroll
    for (int jf = 0; jf < 11; ++jf)
#pragma unroll
        for (int r = 0; r < 4; ++r) {
            float e = __expf(acS[jf][r] - mx[r]);
            acS[jf][r] = e;
            sm[r] += e;
        }
#pragma unroll
    for (int r = 0; r < 4; ++r) {
#pragma unroll
        for (int off = 8; off; off >>= 1) sm[r] += __shfl_xor(sm[r], off);
        sm[r] = 1.f / sm[r];
    }
    __syncthreads();   // all waves done reading Qu/Qv/Kl/Pp

    // ---- write P (A-frag layout, own rows) + zero pad cols [176,192) ----
#pragma unroll
    for (int jf = 0; jf < 11; ++jf)
#pragma unroll
        for (int r = 0; r < 4; ++r)
            Pl[(m0 + (lane >> 4) * 4 + r) * 200 + jf * 16 + lr] = f2bf(acS[jf][r]);
#pragma unroll
    for (int r = 0; r < 4; ++r)
        Pl[(m0 + (lane >> 4) * 4 + r) * 200 + 176 + lr] = 0;

    // ---- stage V row-major, d0-subtiled [4][192][16], via global_load_lds spans ----
    for (int sp = w; sp < 24; sp += 4) {
        const int ob = sp * 1024 + lane * 16;     // byte offset in Vsub
        const int d0c = ob / 6144;
        const int rem = ob - d0c * 6144;
        const int j = rem >> 5;
        const int halfo = (rem & 31) >> 4;
        int t = t0 - HALFW + j; t = t < 0 ? 0 : (t < TSEQ ? t : TSEQ - 1);
        const ushort* src = qkv + (size_t)(b * TSEQ + t) * QKVDIM + 2 * CDIM
                            + h * DKK + d0c * 16 + halfo * 8;
        gload_lds16(src, (char*)Vsub + sp * 1024);
    }
    __syncthreads();   // drains vmcnt (gload) + orders Pl writes

    // ---- PV: O[16][64] = P[16][192] x V[192][64], B-frags via ds_read_b64_tr_b16 ----
    s16x8 pa[6];
#pragma unroll
    for (int ks = 0; ks < 6; ++ks)
        pa[ks] = *(const s16x8*)&Pl[(m0 + lr) * 200 + ks * 32 + lk];
    const unsigned vbase = LDSOFF(Vsub);
    f32x4 acO[4] = {};
#pragma unroll
    for (int nf = 0; nf < 4; ++nf) {
        const unsigned abase = vbase + nf * 6144 + ((lane >> 4) << 8) + ((lane & 15) << 1);
        s16x4 lo[6], hi[6];
#pragma unroll
        for (int ks = 0; ks < 6; ++ks) {
            lo[ks] = tr_read(abase + ks * 1024);
            hi[ks] = tr_read128(abase + ks * 1024);
        }
        asm volatile("s_waitcnt lgkmcnt(0)" ::: "memory");
        __builtin_amdgcn_sched_barrier(0);
#pragma unroll
        for (int ks = 0; ks < 6; ++ks) {
            s16x8 vb = __builtin_shufflevector(lo[ks], hi[ks], 0, 1, 2, 3, 4, 5, 6, 7);
            acO[nf] = __builtin_amdgcn_mfma_f32_16x16x32_bf16(pa[ks], vb, acO[nf], 0, 0, 0);
        }
    }
#pragma unroll
    for (int nf = 0; nf < 4; ++nf)
#pragma unroll
        for (int r = 0; r < 4; ++r) {
            const int t = t0 + m0 + (lane >> 4) * 4 + r;
            if (t < TSEQ)
                o[(size_t)(b * TSEQ + t) * CDIM + h * DKK + nf * 16 + lr] =
                    f2bf(acO[nf][r] * sm[r]);
        }
}

// ---------------- launch ----------------
extern "C" void kernel_launch(void* const* d_in, const int* in_sizes, int n_in,
                              void* d_out, int out_size, void* d_ws, size_t ws_size,
                              hipStream_t stream) {
    const float* x     = (const float*)d_in[0];
    const float* Wq    = (const float*)d_in[1];
    const float* bq    = (const float*)d_in[2];
    const float* Wk    = (const float*)d_in[3];
    const float* bk    = (const float*)d_in[4];
    const float* Wv    = (const float*)d_in[5];
    const float* bv    = (const float*)d_in[6];
    const float* Wo    = (const float*)d_in[7];
    const float* bo    = (const float*)d_in[8];
    const float* Wp    = (const float*)d_in[9];
    const float* pos_u = (const float*)d_in[10];
    const float* pos_v = (const float*)d_in[11];
    const float* ln1g  = (const float*)d_in[12];
    const float* ln1b  = (const float*)d_in[13];
    const float* ln2g  = (const float*)d_in[14];
    const float* ln2b  = (const float*)d_in[15];
    const float* W1    = (const float*)d_in[16];
    const float* b1    = (const float*)d_in[17];
    const float* W2    = (const float*)d_in[18];
    const float* b2    = (const float*)d_in[19];

    float* h = (float*)d_out;
    const float XS = 27.712812921102035f;   // sqrt(768)

    char* p = (char*)d_ws;
    ushort* Wtqkv = (ushort*)p;               p += (size_t)LNUM * QKVDIM * CDIM * 2;
    ushort* Wtp   = (ushort*)p;               p += (size_t)LNUM * CDIM * CDIM * 2;
    ushort* Wto   = (ushort*)p;               p += (size_t)LNUM * CDIM * CDIM * 2;
    ushort* Wt1   = (ushort*)p;               p += (size_t)LNUM * CDIM * CDIM * 2;
    ushort* Wt2   = (ushort*)p;               p += (size_t)LNUM * CDIM * CDIM * 2;
    float*  bqkv  = (float*)p;                p += (size_t)LNUM * QKVDIM * 4;
    ushort* pe    = (ushort*)p;               p += (size_t)2048 * CDIM * 2;
    ushort* pb    = (ushort*)p;               p += (size_t)LNUM * 2048 * CDIM * 2;
    ushort* y     = (ushort*)p;               p += (size_t)MPAD * CDIM * 2;
    ushort* qkv   = (ushort*)p;               p += (size_t)MPAD * QKVDIM * 2;
    ushort* o     = (ushort*)p;               p += (size_t)MPAD * CDIM * 2;
    ushort* hid   = (ushort*)p;               p += (size_t)MPAD * CDIM * 2;

    transpose_pack<<<dim3(24, 24, LNUM * 7), dim3(32, 8), 0, stream>>>(
        Wq, Wk, Wv, Wp, Wo, W1, W2, Wtqkv, Wtp, Wto, Wt1, Wt2);
    prep_small<<<384, 256, 0, stream>>>(pe, bq, bk, bv, bqkv);

    const dim3 gQKV(32, QKVDIM / 128);
    const dim3 gC(32, CDIM / 128);
    const dim3 gP(2, CDIM / 128);
    const dim3 gA(16, HHEADS, BBATCH);

    // rel-pos projections for both layers, off the critical path
    for (int l = 0; l < LNUM; ++l)
        gemm_mfma<0><<<gP, 256, 0, stream>>>(pe + (size_t)896 * CDIM,
                                             Wtp + (size_t)l * CDIM * CDIM, nullptr,
                                             pb + (size_t)l * 2048 * CDIM + (size_t)896 * CDIM,
                                             256, CDIM, nullptr, 0.f);

    for (int l = 0; l < LNUM; ++l) {
        const size_t wo = (size_t)l * CDIM * CDIM;
        const float* res1 = (l == 0) ? x : h;
        const float rs1   = (l == 0) ? XS : 1.f;
        ln_kernel<<<MROWS, 192, 0, stream>>>(res1, ln1g + l * CDIM, ln1b + l * CDIM, y, rs1);
        gemm_mfma<0><<<gQKV, 256, 0, stream>>>(y, Wtqkv + (size_t)l * QKVDIM * CDIM,
                                               bqkv + l * QKVDIM, qkv, MROWS, QKVDIM,
                                               nullptr, 0.f);
        attn_mfma<<<gA, 256, 0, stream>>>(
            qkv, pb + (size_t)l * 2048 * CDIM,
            pos_u + l * HHEADS * DKK, pos_v + l * HHEADS * DKK, o);
        gemm_mfma<2><<<gC, 256, 0, stream>>>(o, Wto + wo, bo + l * CDIM, h, MROWS, CDIM,
                                             res1, rs1);
        ln_kernel<<<MROWS, 192, 0, stream>>>(h, ln2g + l * CDIM, ln2b + l * CDIM, y, 1.f);
        gemm_mfma<1><<<gC, 256, 0, stream>>>(y, Wt1 + wo, b1 + l * CDIM, hid, MROWS, CDIM,
                                             nullptr, 0.f);
        gemm_mfma<2><<<gC, 256, 0, stream>>>(hid, Wt2 + wo, b2 + l * CDIM, h, MROWS, CDIM,
                                             h, 1.f);
    }
}

// Round 5
// 350.307 us; speedup vs baseline: 5.9791x; 1.0961x over previous
//
#include <hip/hip_runtime.h>
#include <math.h>

#define LNUM 2
#define BBATCH 4
#define TSEQ 1000
#define CDIM 768
#define HHEADS 12
#define DKK 64
#define PPOS (2*TSEQ-1)   // 1999
#define HALFW 50
#define MROWS (BBATCH*TSEQ)     // 4000
#define MPAD 4096
#define QKVDIM (3*CDIM)         // 2304
#define NS 176                  // real key span per 64-query tile (padded to 192)

typedef __attribute__((ext_vector_type(8))) short s16x8;
typedef __attribute__((ext_vector_type(4))) short s16x4;
typedef __attribute__((ext_vector_type(4))) float f32x4;

#define LDSOFF(p) ((unsigned)(uintptr_t)(__attribute__((address_space(3))) const void*)(p))

__device__ __forceinline__ ushort f2bf(float x) {
    unsigned u = __float_as_uint(x);
    unsigned r = u + 0x7FFFu + ((u >> 16) & 1u);
    return (ushort)(r >> 16);
}
__device__ __forceinline__ float bf2f(ushort h) {
    return __uint_as_float(((unsigned)h) << 16);
}
__device__ __forceinline__ float gelu_f(float x) {
    float u = 0.7978845608028654f * (x + 0.044715f * x * x * x);
    return 0.5f * x * (1.f + tanhf(u));
}
__device__ __forceinline__ void gload_lds16(const void* g, void* l) {
    __builtin_amdgcn_global_load_lds(
        (const __attribute__((address_space(1))) void*)g,
        (__attribute__((address_space(3))) void*)l, 16, 0, 0);
}
__device__ __forceinline__ s16x4 tr_read(unsigned addr) {
    s16x4 d;
    asm volatile("ds_read_b64_tr_b16 %0, %1" : "=v"(d) : "v"(addr));
    return d;
}
__device__ __forceinline__ s16x4 tr_read128(unsigned addr) {
    s16x4 d;
    asm volatile("ds_read_b64_tr_b16 %0, %1 offset:128" : "=v"(d) : "v"(addr));
    return d;
}

// ---------------- weight transpose + bf16 convert ----------------
__global__ __launch_bounds__(256) void transpose_pack(
    const float* __restrict__ Wq, const float* __restrict__ Wk,
    const float* __restrict__ Wv, const float* __restrict__ Wp,
    const float* __restrict__ Wo, const float* __restrict__ W1,
    const float* __restrict__ W2,
    ushort* __restrict__ Wtqkv, ushort* __restrict__ Wtp,
    ushort* __restrict__ Wto, ushort* __restrict__ Wt1, ushort* __restrict__ Wt2) {
    const int l = blockIdx.z / 7, m = blockIdx.z % 7;
    const float* srcs[7] = {Wq, Wk, Wv, Wp, Wo, W1, W2};
    const float* src = srcs[m] + (size_t)l * CDIM * CDIM;
    ushort* dst;
    if (m < 3)       dst = Wtqkv + (size_t)l * QKVDIM * CDIM + (size_t)m * CDIM * CDIM;
    else if (m == 3) dst = Wtp + (size_t)l * CDIM * CDIM;
    else if (m == 4) dst = Wto + (size_t)l * CDIM * CDIM;
    else if (m == 5) dst = Wt1 + (size_t)l * CDIM * CDIM;
    else             dst = Wt2 + (size_t)l * CDIM * CDIM;
    __shared__ float tile[32][33];
    const int tx = threadIdx.x, ty = threadIdx.y;       // (32, 8)
    const int c0 = blockIdx.x * 32, r0 = blockIdx.y * 32;
#pragma unroll
    for (int i = 0; i < 4; ++i)
        tile[ty + i * 8][tx] = src[(size_t)(r0 + ty + i * 8) * CDIM + c0 + tx];
    __syncthreads();
#pragma unroll
    for (int i = 0; i < 4; ++i)
        dst[(size_t)(c0 + ty + i * 8) * CDIM + r0 + tx] = f2bf(tile[tx][ty + i * 8]);
}

// ---------------- fused small prep: pos-enc rows [896,1152) + qkv bias pack ----------------
__global__ __launch_bounds__(256) void prep_small(ushort* __restrict__ pe,
                                                  const float* __restrict__ bq,
                                                  const float* __restrict__ bk,
                                                  const float* __restrict__ bv,
                                                  float* __restrict__ bqkv) {
    int idx = blockIdx.x * 256 + threadIdx.x;
    const int npair = 256 * (CDIM / 2);
    if (idx < npair) {
        int jloc = idx / (CDIM / 2);
        int m = idx - jloc * (CDIM / 2);
        int j = 896 + jloc;
        float rel = (float)(TSEQ - 1 - j);
        float div = expf(-(float)(2 * m) * (9.210340371976184f / (float)CDIM));
        float a = rel * div;
        pe[(size_t)j * CDIM + 2 * m]     = f2bf(sinf(a));
        pe[(size_t)j * CDIM + 2 * m + 1] = f2bf(cosf(a));
    }
    if (idx < LNUM * QKVDIM) {
        int l = idx / QKVDIM, c = idx - l * QKVDIM;
        float v;
        if (c < CDIM)            v = bq[l * CDIM + c];
        else if (c < 2 * CDIM)   v = bk[l * CDIM + c - CDIM];
        else                     v = bv[l * CDIM + c - 2 * CDIM];
        bqkv[idx] = v;
    }
}

// ---------------- LayerNorm: f32 in (xscale-on-load), bf16 out; 192 thr, float4 ----------------
__global__ __launch_bounds__(192) void ln_kernel(const float* __restrict__ in,
                                                 const float* __restrict__ g,
                                                 const float* __restrict__ bta,
                                                 ushort* __restrict__ y, float xscale) {
    const int row = blockIdx.x, tid = threadIdx.x;
    float4 v = *(const float4*)&in[(size_t)row * CDIM + tid * 4];
    v.x *= xscale; v.y *= xscale; v.z *= xscale; v.w *= xscale;
    float s  = v.x + v.y + v.z + v.w;
    float ss = v.x * v.x + v.y * v.y + v.z * v.z + v.w * v.w;
#pragma unroll
    for (int off = 32; off; off >>= 1) {
        s  += __shfl_xor(s, off);
        ss += __shfl_xor(ss, off);
    }
    __shared__ float sm[3], sq[3];
    const int wid = tid >> 6, lane = tid & 63;
    if (lane == 0) { sm[wid] = s; sq[wid] = ss; }
    __syncthreads();
    const float st  = sm[0] + sm[1] + sm[2];
    const float sst = sq[0] + sq[1] + sq[2];
    const float mean = st * (1.f / CDIM);
    const float var  = sst * (1.f / CDIM) - mean * mean;
    const float rstd = rsqrtf(var + 1e-5f);
    const float4 g4 = *(const float4*)&g[tid * 4];
    const float4 b4 = *(const float4*)&bta[tid * 4];
    ushort o0 = f2bf((v.x - mean) * rstd * g4.x + b4.x);
    ushort o1 = f2bf((v.y - mean) * rstd * g4.y + b4.y);
    ushort o2 = f2bf((v.z - mean) * rstd * g4.z + b4.z);
    ushort o3 = f2bf((v.w - mean) * rstd * g4.w + b4.w);
    uint2 pk; pk.x = (unsigned)o0 | ((unsigned)o1 << 16);
    pk.y = (unsigned)o2 | ((unsigned)o3 << 16);
    *(uint2*)&y[(size_t)row * CDIM + tid * 4] = pk;
}

// ---------------- MFMA bf16 GEMM ----------------
// EPI 0: bf16 store; 1: gelu->bf16 store; 2: Out(f32) = resid*rscale + acc + bias
// zsB/zsO: per-blockIdx.z element strides (batched variant; 0 when grid.z==1)
template <int EPI>
__global__ __launch_bounds__(256, 3) void gemm_mfma(const ushort* __restrict__ A,
                                                    const ushort* __restrict__ Bt,
                                                    const float* __restrict__ bias,
                                                    void* Out, int M, int ldo,
                                                    const float* resid, float rscale,
                                                    size_t zsB, size_t zsO) {
    __shared__ ushort lds[8192];
    const int tid = threadIdx.x;
    const int w = tid >> 6, lane = tid & 63;
    const int row0 = blockIdx.x * 128, col0 = blockIdx.y * 128;
    const size_t zb = blockIdx.z;
    Bt += zb * zsB;
    if (EPI == 2) Out = (void*)((float*)Out + zb * zsO);
    else          Out = (void*)((ushort*)Out + zb * zsO);
    const int subrow = lane >> 2;
    const int kchunk = (lane & 3) * 8;
    f32x4 acc[4][4] = {};
    for (int k0 = 0; k0 < CDIM; k0 += 32) {
        __syncthreads();
#pragma unroll
        for (int c = 0; c < 4; ++c) {
            const int r = (w & 1) * 64 + c * 16 + subrow;
            const ushort* src = (w < 2)
                ? A  + (size_t)(row0 + r) * CDIM + k0 + kchunk
                : Bt + (size_t)(col0 + r) * CDIM + k0 + kchunk;
            gload_lds16(src, (char*)lds + w * 4096 + c * 1024);
        }
        __syncthreads();
        const int wm = (w >> 1) * 64, wn = (w & 1) * 64;
        s16x8 af[4], bfr[4];
#pragma unroll
        for (int i = 0; i < 4; ++i)
            af[i] = *(const s16x8*)&lds[(wm + i * 16 + (lane & 15)) * 32 + (lane >> 4) * 8];
#pragma unroll
        for (int j = 0; j < 4; ++j)
            bfr[j] = *(const s16x8*)&lds[(128 + wn + j * 16 + (lane & 15)) * 32 + (lane >> 4) * 8];
#pragma unroll
        for (int i = 0; i < 4; ++i)
#pragma unroll
            for (int j = 0; j < 4; ++j)
                acc[i][j] = __builtin_amdgcn_mfma_f32_16x16x32_bf16(af[i], bfr[j], acc[i][j], 0, 0, 0);
    }
    const int crow0 = row0 + (w >> 1) * 64;
    const int ccol0 = col0 + (w & 1) * 64;
    const int lr = (lane >> 4) * 4;
    const int lc = lane & 15;
#pragma unroll
    for (int j = 0; j < 4; ++j) {
        const int col = ccol0 + j * 16 + lc;
        const float bv = bias ? bias[col] : 0.f;
#pragma unroll
        for (int i = 0; i < 4; ++i) {
#pragma unroll
            for (int r = 0; r < 4; ++r) {
                const int row = crow0 + i * 16 + lr + r;
                if (row >= M) continue;
                const float v = acc[i][j][r] + bv;
                if (EPI == 0)
                    ((ushort*)Out)[(size_t)row * ldo + col] = f2bf(v);
                else if (EPI == 1)
                    ((ushort*)Out)[(size_t)row * ldo + col] = f2bf(gelu_f(v));
                else {
                    float* p = (float*)Out + (size_t)row * ldo + col;
                    *p = resid[(size_t)row * ldo + col] * rscale + v;
                }
            }
        }
    }
}

// ---------------- MFMA banded rel-pos attention ----------------
// Block = (b, h, 64-query tile). Keys [t0-50, t0+125] -> 176 cols (+16 zero-P pad).
// rel_shift identity: u = j - tloc, p row = 949 + u.
// LDS 49 KB -> 3 blocks/CU. Phase1: Kl[176][72] @0, Qraw[64][72] @25344,
// Bd[4][16][104] @34560. Phase2: Pl[64][200] @0, Vsub[4][192][16] @25600.
__global__ __launch_bounds__(256, 3) void attn_mfma(
    const ushort* __restrict__ qkv, const ushort* __restrict__ pb,
    const float* __restrict__ pos_u, const float* __restrict__ pos_v,
    ushort* __restrict__ o) {
    __shared__ __align__(16) char smem[50176];
    ushort* Kl   = (ushort*)smem;               // [176][72]
    ushort* Qraw = (ushort*)(smem + 25344);     // [64][72]
    ushort* Bd   = (ushort*)(smem + 34560);     // [4][16][104]
    ushort* Pl   = (ushort*)smem;               // phase2: [64][200]
    ushort* Vsub = (ushort*)(smem + 25600);     // phase2: [4 d0][192 j][16 d]

    const int tid = threadIdx.x;
    const int w = tid >> 6, lane = tid & 63;
    const int t0 = blockIdx.x * 64;
    const int h = blockIdx.y, b = blockIdx.z;

    // ---- stage Qraw (one 16-elem chunk per thread) ----
    {
        const int row = tid >> 2, c = (tid & 3) << 4;
        int t = t0 + row; t = (t < TSEQ) ? t : TSEQ - 1;
        const ushort* qp = qkv + (size_t)(b * TSEQ + t) * QKVDIM + h * DKK + c;
        *(s16x8*)&Qraw[row * 72 + c]     = *(const s16x8*)qp;
        *(s16x8*)&Qraw[row * 72 + c + 8] = *(const s16x8*)(qp + 8);
    }
    // ---- stage K ----
    for (int task = tid; task < NS * 4; task += 256) {
        const int j = task >> 2, c = (task & 3) << 4;
        int kb = t0 - HALFW + j; kb = kb < 0 ? 0 : (kb < TSEQ ? kb : TSEQ - 1);
        const ushort* kp = qkv + (size_t)(b * TSEQ + kb) * QKVDIM + CDIM + h * DKK + c;
        *(s16x8*)&Kl[j * 72 + c]     = *(const s16x8*)kp;
        *(s16x8*)&Kl[j * 72 + c + 8] = *(const s16x8*)(kp + 8);
    }
    __syncthreads();

    const int m0 = w * 16;
    const int lr = lane & 15, lk = (lane >> 4) * 8;
    const f32x4 zero = {0.f, 0.f, 0.f, 0.f};

    // ---- rel-pos B-fragments straight from global (L2-hot, 14 KB/head) ----
    const ushort* pbh = pb + (size_t)949 * CDIM + h * DKK;
    s16x8 pfr[7][2];
#pragma unroll
    for (int uf = 0; uf < 7; ++uf) {
        pfr[uf][0] = *(const s16x8*)&pbh[(size_t)(uf * 16 + lr) * CDIM + lk];
        pfr[uf][1] = *(const s16x8*)&pbh[(size_t)(uf * 16 + lr) * CDIM + 32 + lk];
    }

    // ---- build qu/qv fragments in regs from Qraw + pos vectors ----
    s16x8 qr0 = *(const s16x8*)&Qraw[(m0 + lr) * 72 + lk];
    s16x8 qr1 = *(const s16x8*)&Qraw[(m0 + lr) * 72 + 32 + lk];
    s16x8 qu0, qu1, qv0, qv1;
#pragma unroll
    for (int e = 0; e < 8; ++e) {
        const float q0 = bf2f((ushort)qr0[e]), q1 = bf2f((ushort)qr1[e]);
        qu0[e] = (short)f2bf(q0 + pos_u[h * DKK + lk + e]);
        qu1[e] = (short)f2bf(q1 + pos_u[h * DKK + 32 + lk + e]);
        qv0[e] = (short)f2bf(q0 + pos_v[h * DKK + lk + e]);
        qv1[e] = (short)f2bf(q1 + pos_v[h * DKK + 32 + lk + e]);
    }

    // ---- score MFMAs ----
    f32x4 acS[11], acB[7];
    __builtin_amdgcn_s_setprio(1);
#pragma unroll
    for (int uf = 0; uf < 7; ++uf) {
        acB[uf] = __builtin_amdgcn_mfma_f32_16x16x32_bf16(qv0, pfr[uf][0], zero, 0, 0, 0);
        acB[uf] = __builtin_amdgcn_mfma_f32_16x16x32_bf16(qv1, pfr[uf][1], acB[uf], 0, 0, 0);
    }
#pragma unroll
    for (int jf = 0; jf < 11; ++jf) {
        s16x8 k0 = *(const s16x8*)&Kl[(jf * 16 + lr) * 72 + lk];
        s16x8 k1 = *(const s16x8*)&Kl[(jf * 16 + lr) * 72 + 32 + lk];
        acS[jf] = __builtin_amdgcn_mfma_f32_16x16x32_bf16(qu0, k0, zero, 0, 0, 0);
        acS[jf] = __builtin_amdgcn_mfma_f32_16x16x32_bf16(qu1, k1, acS[jf], 0, 0, 0);
    }
    __builtin_amdgcn_s_setprio(0);

    // ---- bd -> LDS (own-wave region) ----
    ushort* bdw = Bd + w * 16 * 104;
#pragma unroll
    for (int uf = 0; uf < 7; ++uf)
#pragma unroll
        for (int r = 0; r < 4; ++r)
            bdw[((lane >> 4) * 4 + r) * 104 + uf * 16 + lr] = f2bf(acB[uf][r]);
    // ---- combine + masked softmax (deferred 1/sum) ----
    float mx[4] = {-1e30f, -1e30f, -1e30f, -1e30f};
#pragma unroll
    for (int jf = 0; jf < 11; ++jf)
#pragma unroll
        for (int r = 0; r < 4; ++r) {
            const int tl = (lane >> 4) * 4 + r;
            const int tloc = m0 + tl;
            const int j = jf * 16 + lr;
            const int u = j - tloc;
            const int s = t0 - HALFW + j;
            const bool valid = (u >= 0) & (u <= 2 * HALFW) & (s >= 0) & (s < TSEQ)
                               & (t0 + tloc < TSEQ);
            float sc = -1e30f;
            if (valid) sc = (acS[jf][r] + bf2f(bdw[tl * 104 + u])) * 0.125f;
            acS[jf][r] = sc;
            mx[r] = fmaxf(mx[r], sc);
        }
#pragma unroll
    for (int r = 0; r < 4; ++r)
#pragma unroll
        for (int off = 8; off; off >>= 1)
            mx[r] = fmaxf(mx[r], __shfl_xor(mx[r], off));
    float sm[4] = {0.f, 0.f, 0.f, 0.f};
#pragma unroll
    for (int jf = 0; jf < 11; ++jf)
#pragma unroll
        for (int r = 0; r < 4; ++r) {
            float e = __expf(acS[jf][r] - mx[r]);
            acS[jf][r] = e;
            sm[r] += e;
        }
#pragma unroll
    for (int r = 0; r < 4; ++r) {
#pragma unroll
        for (int off = 8; off; off >>= 1) sm[r] += __shfl_xor(sm[r], off);
        sm[r] = 1.f / sm[r];
    }
    __syncthreads();   // all waves done reading Kl/Qraw & own Bd

    // ---- write P (A-frag layout, own rows) + zero pad cols [176,192) ----
#pragma unroll
    for (int jf = 0; jf < 11; ++jf)
#pragma unroll
        for (int r = 0; r < 4; ++r)
            Pl[(m0 + (lane >> 4) * 4 + r) * 200 + jf * 16 + lr] = f2bf(acS[jf][r]);
#pragma unroll
    for (int r = 0; r < 4; ++r)
        Pl[(m0 + (lane >> 4) * 4 + r) * 200 + 176 + lr] = 0;

    // ---- stage V row-major, d0-subtiled [4][192][16], via global_load_lds spans ----
    for (int sp = w; sp < 24; sp += 4) {
        const int ob = sp * 1024 + lane * 16;     // byte offset in Vsub
        const int d0c = ob / 6144;
        const int rem = ob - d0c * 6144;
        const int j = rem >> 5;
        const int halfo = (rem & 31) >> 4;
        int t = t0 - HALFW + j; t = t < 0 ? 0 : (t < TSEQ ? t : TSEQ - 1);
        const ushort* src = qkv + (size_t)(b * TSEQ + t) * QKVDIM + 2 * CDIM
                            + h * DKK + d0c * 16 + halfo * 8;
        gload_lds16(src, (char*)Vsub + sp * 1024);
    }
    __syncthreads();   // drains vmcnt (gload) + orders Pl writes

    // ---- PV: O[16][64] = P[16][192] x V[192][64], B-frags via ds_read_b64_tr_b16 ----
    s16x8 pa[6];
#pragma unroll
    for (int ks = 0; ks < 6; ++ks)
        pa[ks] = *(const s16x8*)&Pl[(m0 + lr) * 200 + ks * 32 + lk];
    const unsigned vbase = LDSOFF(Vsub);
    f32x4 acO[4] = {};
#pragma unroll
    for (int nf = 0; nf < 4; ++nf) {
        const unsigned abase = vbase + nf * 6144 + ((lane >> 4) << 8) + ((lane & 15) << 1);
        s16x4 lo[6], hi[6];
#pragma unroll
        for (int ks = 0; ks < 6; ++ks) {
            lo[ks] = tr_read(abase + ks * 1024);
            hi[ks] = tr_read128(abase + ks * 1024);
        }
        asm volatile("s_waitcnt lgkmcnt(0)" ::: "memory");
        __builtin_amdgcn_sched_barrier(0);
        __builtin_amdgcn_s_setprio(1);
#pragma unroll
        for (int ks = 0; ks < 6; ++ks) {
            s16x8 vb = __builtin_shufflevector(lo[ks], hi[ks], 0, 1, 2, 3, 4, 5, 6, 7);
            acO[nf] = __builtin_amdgcn_mfma_f32_16x16x32_bf16(pa[ks], vb, acO[nf], 0, 0, 0);
        }
        __builtin_amdgcn_s_setprio(0);
    }
#pragma unroll
    for (int nf = 0; nf < 4; ++nf)
#pragma unroll
        for (int r = 0; r < 4; ++r) {
            const int t = t0 + m0 + (lane >> 4) * 4 + r;
            if (t < TSEQ)
                o[(size_t)(b * TSEQ + t) * CDIM + h * DKK + nf * 16 + lr] =
                    f2bf(acO[nf][r] * sm[r]);
        }
}

// ---------------- launch ----------------
extern "C" void kernel_launch(void* const* d_in, const int* in_sizes, int n_in,
                              void* d_out, int out_size, void* d_ws, size_t ws_size,
                              hipStream_t stream) {
    const float* x     = (const float*)d_in[0];
    const float* Wq    = (const float*)d_in[1];
    const float* bq    = (const float*)d_in[2];
    const float* Wk    = (const float*)d_in[3];
    const float* bk    = (const float*)d_in[4];
    const float* Wv    = (const float*)d_in[5];
    const float* bv    = (const float*)d_in[6];
    const float* Wo    = (const float*)d_in[7];
    const float* bo    = (const float*)d_in[8];
    const float* Wp    = (const float*)d_in[9];
    const float* pos_u = (const float*)d_in[10];
    const float* pos_v = (const float*)d_in[11];
    const float* ln1g  = (const float*)d_in[12];
    const float* ln1b  = (const float*)d_in[13];
    const float* ln2g  = (const float*)d_in[14];
    const float* ln2b  = (const float*)d_in[15];
    const float* W1    = (const float*)d_in[16];
    const float* b1    = (const float*)d_in[17];
    const float* W2    = (const float*)d_in[18];
    const float* b2    = (const float*)d_in[19];

    float* h = (float*)d_out;
    const float XS = 27.712812921102035f;   // sqrt(768)

    char* p = (char*)d_ws;
    ushort* Wtqkv = (ushort*)p;               p += (size_t)LNUM * QKVDIM * CDIM * 2;
    ushort* Wtp   = (ushort*)p;               p += (size_t)LNUM * CDIM * CDIM * 2;
    ushort* Wto   = (ushort*)p;               p += (size_t)LNUM * CDIM * CDIM * 2;
    ushort* Wt1   = (ushort*)p;               p += (size_t)LNUM * CDIM * CDIM * 2;
    ushort* Wt2   = (ushort*)p;               p += (size_t)LNUM * CDIM * CDIM * 2;
    float*  bqkv  = (float*)p;                p += (size_t)LNUM * QKVDIM * 4;
    ushort* pe    = (ushort*)p;               p += (size_t)2048 * CDIM * 2;
    ushort* pb    = (ushort*)p;               p += (size_t)LNUM * 2048 * CDIM * 2;
    ushort* y     = (ushort*)p;               p += (size_t)MPAD * CDIM * 2;
    ushort* qkv   = (ushort*)p;               p += (size_t)MPAD * QKVDIM * 2;
    ushort* o     = (ushort*)p;               p += (size_t)MPAD * CDIM * 2;
    ushort* hid   = (ushort*)p;               p += (size_t)MPAD * CDIM * 2;

    transpose_pack<<<dim3(24, 24, LNUM * 7), dim3(32, 8), 0, stream>>>(
        Wq, Wk, Wv, Wp, Wo, W1, W2, Wtqkv, Wtp, Wto, Wt1, Wt2);
    prep_small<<<384, 256, 0, stream>>>(pe, bq, bk, bv, bqkv);

    const dim3 gQKV(32, QKVDIM / 128);
    const dim3 gC(32, CDIM / 128);
    const dim3 gP(2, CDIM / 128, LNUM);     // both layers' P-projections in one dispatch
    const dim3 gA(16, HHEADS, BBATCH);

    gemm_mfma<0><<<gP, 256, 0, stream>>>(pe + (size_t)896 * CDIM, Wtp, nullptr,
                                         pb + (size_t)896 * CDIM, 256, CDIM,
                                         nullptr, 0.f,
                                         (size_t)CDIM * CDIM, (size_t)2048 * CDIM);

    for (int l = 0; l < LNUM; ++l) {
        const size_t wo = (size_t)l * CDIM * CDIM;
        const float* res1 = (l == 0) ? x : h;
        const float rs1   = (l == 0) ? XS : 1.f;
        ln_kernel<<<MROWS, 192, 0, stream>>>(res1, ln1g + l * CDIM, ln1b + l * CDIM, y, rs1);
        gemm_mfma<0><<<gQKV, 256, 0, stream>>>(y, Wtqkv + (size_t)l * QKVDIM * CDIM,
                                               bqkv + l * QKVDIM, qkv, MROWS, QKVDIM,
                                               nullptr, 0.f, 0, 0);
        attn_mfma<<<gA, 256, 0, stream>>>(
            qkv, pb + (size_t)l * 2048 * CDIM,
            pos_u + l * HHEADS * DKK, pos_v + l * HHEADS * DKK, o);
        gemm_mfma<2><<<gC, 256, 0, stream>>>(o, Wto + wo, bo + l * CDIM, h, MROWS, CDIM,
                                             res1, rs1, 0, 0);
        ln_kernel<<<MROWS, 192, 0, stream>>>(h, ln2g + l * CDIM, ln2b + l * CDIM, y, 1.f);
        gemm_mfma<1><<<gC, 256, 0, stream>>>(y, Wt1 + wo, b1 + l * CDIM, hid, MROWS, CDIM,
                                             nullptr, 0.f, 0, 0);
        gemm_mfma<2><<<gC, 256, 0, stream>>>(hid, Wt2 + wo, b2 + l * CDIM, h, MROWS, CDIM,
                                             h, 1.f, 0, 0);
    }
}

// Round 6
// 328.503 us; speedup vs baseline: 6.3760x; 1.0664x over previous
//
#include <hip/hip_runtime.h>
#include <math.h>

#define LNUM 2
#define BBATCH 4
#define TSEQ 1000
#define CDIM 768
#define HHEADS 12
#define DKK 64
#define PPOS (2*TSEQ-1)   // 1999
#define HALFW 50
#define MROWS (BBATCH*TSEQ)     // 4000
#define MPAD 4096
#define QKVDIM (3*CDIM)         // 2304
#define NS 176                  // real key span per 64-query tile (padded to 192)

typedef __attribute__((ext_vector_type(8))) short s16x8;
typedef __attribute__((ext_vector_type(4))) short s16x4;
typedef __attribute__((ext_vector_type(4))) float f32x4;

#define LDSOFF(p) ((unsigned)(uintptr_t)(__attribute__((address_space(3))) const void*)(p))

__device__ __forceinline__ ushort f2bf(float x) {
    unsigned u = __float_as_uint(x);
    unsigned r = u + 0x7FFFu + ((u >> 16) & 1u);
    return (ushort)(r >> 16);
}
__device__ __forceinline__ float bf2f(ushort h) {
    return __uint_as_float(((unsigned)h) << 16);
}
__device__ __forceinline__ float gelu_f(float x) {
    float u = 0.7978845608028654f * (x + 0.044715f * x * x * x);
    return 0.5f * x * (1.f + tanhf(u));
}
__device__ __forceinline__ void gload_lds16(const void* g, void* l) {
    __builtin_amdgcn_global_load_lds(
        (const __attribute__((address_space(1))) void*)g,
        (__attribute__((address_space(3))) void*)l, 16, 0, 0);
}
__device__ __forceinline__ s16x4 tr_read(unsigned addr) {
    s16x4 d;
    asm volatile("ds_read_b64_tr_b16 %0, %1" : "=v"(d) : "v"(addr));
    return d;
}
__device__ __forceinline__ s16x4 tr_read128(unsigned addr) {
    s16x4 d;
    asm volatile("ds_read_b64_tr_b16 %0, %1 offset:128" : "=v"(d) : "v"(addr));
    return d;
}

// ---------------- weight transpose + bf16 convert ----------------
__global__ __launch_bounds__(256) void transpose_pack(
    const float* __restrict__ Wq, const float* __restrict__ Wk,
    const float* __restrict__ Wv, const float* __restrict__ Wp,
    const float* __restrict__ Wo, const float* __restrict__ W1,
    const float* __restrict__ W2,
    ushort* __restrict__ Wtqkv, ushort* __restrict__ Wtp,
    ushort* __restrict__ Wto, ushort* __restrict__ Wt1, ushort* __restrict__ Wt2) {
    const int l = blockIdx.z / 7, m = blockIdx.z % 7;
    const float* srcs[7] = {Wq, Wk, Wv, Wp, Wo, W1, W2};
    const float* src = srcs[m] + (size_t)l * CDIM * CDIM;
    ushort* dst;
    if (m < 3)       dst = Wtqkv + (size_t)l * QKVDIM * CDIM + (size_t)m * CDIM * CDIM;
    else if (m == 3) dst = Wtp + (size_t)l * CDIM * CDIM;
    else if (m == 4) dst = Wto + (size_t)l * CDIM * CDIM;
    else if (m == 5) dst = Wt1 + (size_t)l * CDIM * CDIM;
    else             dst = Wt2 + (size_t)l * CDIM * CDIM;
    __shared__ float tile[32][33];
    const int tx = threadIdx.x, ty = threadIdx.y;       // (32, 8)
    const int c0 = blockIdx.x * 32, r0 = blockIdx.y * 32;
#pragma unroll
    for (int i = 0; i < 4; ++i)
        tile[ty + i * 8][tx] = src[(size_t)(r0 + ty + i * 8) * CDIM + c0 + tx];
    __syncthreads();
#pragma unroll
    for (int i = 0; i < 4; ++i)
        dst[(size_t)(c0 + ty + i * 8) * CDIM + r0 + tx] = f2bf(tile[tx][ty + i * 8]);
}

// ---------------- fused small prep: pos-enc rows [896,1152) + qkv bias pack ----------------
__global__ __launch_bounds__(256) void prep_small(ushort* __restrict__ pe,
                                                  const float* __restrict__ bq,
                                                  const float* __restrict__ bk,
                                                  const float* __restrict__ bv,
                                                  float* __restrict__ bqkv) {
    int idx = blockIdx.x * 256 + threadIdx.x;
    const int npair = 256 * (CDIM / 2);
    if (idx < npair) {
        int jloc = idx / (CDIM / 2);
        int m = idx - jloc * (CDIM / 2);
        int j = 896 + jloc;
        float rel = (float)(TSEQ - 1 - j);
        float div = expf(-(float)(2 * m) * (9.210340371976184f / (float)CDIM));
        float a = rel * div;
        pe[(size_t)j * CDIM + 2 * m]     = f2bf(sinf(a));
        pe[(size_t)j * CDIM + 2 * m + 1] = f2bf(cosf(a));
    }
    if (idx < LNUM * QKVDIM) {
        int l = idx / QKVDIM, c = idx - l * QKVDIM;
        float v;
        if (c < CDIM)            v = bq[l * CDIM + c];
        else if (c < 2 * CDIM)   v = bk[l * CDIM + c - CDIM];
        else                     v = bv[l * CDIM + c - 2 * CDIM];
        bqkv[idx] = v;
    }
}

// ---------------- LayerNorm: f32 in (xscale-on-load), bf16 out; 192 thr, float4 ----------------
__global__ __launch_bounds__(192) void ln_kernel(const float* __restrict__ in,
                                                 const float* __restrict__ g,
                                                 const float* __restrict__ bta,
                                                 ushort* __restrict__ y, float xscale) {
    const int row = blockIdx.x, tid = threadIdx.x;
    float4 v = *(const float4*)&in[(size_t)row * CDIM + tid * 4];
    v.x *= xscale; v.y *= xscale; v.z *= xscale; v.w *= xscale;
    float s  = v.x + v.y + v.z + v.w;
    float ss = v.x * v.x + v.y * v.y + v.z * v.z + v.w * v.w;
#pragma unroll
    for (int off = 32; off; off >>= 1) {
        s  += __shfl_xor(s, off);
        ss += __shfl_xor(ss, off);
    }
    __shared__ float sm[3], sq[3];
    const int wid = tid >> 6, lane = tid & 63;
    if (lane == 0) { sm[wid] = s; sq[wid] = ss; }
    __syncthreads();
    const float st  = sm[0] + sm[1] + sm[2];
    const float sst = sq[0] + sq[1] + sq[2];
    const float mean = st * (1.f / CDIM);
    const float var  = sst * (1.f / CDIM) - mean * mean;
    const float rstd = rsqrtf(var + 1e-5f);
    const float4 g4 = *(const float4*)&g[tid * 4];
    const float4 b4 = *(const float4*)&bta[tid * 4];
    ushort o0 = f2bf((v.x - mean) * rstd * g4.x + b4.x);
    ushort o1 = f2bf((v.y - mean) * rstd * g4.y + b4.y);
    ushort o2 = f2bf((v.z - mean) * rstd * g4.z + b4.z);
    ushort o3 = f2bf((v.w - mean) * rstd * g4.w + b4.w);
    uint2 pk; pk.x = (unsigned)o0 | ((unsigned)o1 << 16);
    pk.y = (unsigned)o2 | ((unsigned)o3 << 16);
    *(uint2*)&y[(size_t)row * CDIM + tid * 4] = pk;
}

// ---------------- MFMA bf16 GEMM, BK=64, XOR-swizzled LDS ----------------
// LDS [256 rows][64 k] (A rows 0-127, B rows 128-255), row stride 128 B.
// Logical k-chunk c (8 ushorts) of row r lives at slot c ^ (r&7)  -> conflict-free
// ds_read_b128; global_load_lds dest stays linear, SOURCE address pre-permuted
// (chunk = (lane&7) ^ (lane>>3), same 128B line -> coalescing preserved).
// EPI 0: bf16 store; 1: gelu->bf16 store; 2: Out(f32) = resid*rscale + acc + bias
template <int EPI>
__global__ __launch_bounds__(256, 3) void gemm_mfma(const ushort* __restrict__ A,
                                                    const ushort* __restrict__ Bt,
                                                    const float* __restrict__ bias,
                                                    void* Out, int M, int ldo,
                                                    const float* resid, float rscale,
                                                    size_t zsB, size_t zsO) {
    __shared__ ushort lds[16384];          // 32 KB
    const int tid = threadIdx.x;
    const int w = tid >> 6, lane = tid & 63;
    const int row0 = blockIdx.x * 128, col0 = blockIdx.y * 128;
    const size_t zb = blockIdx.z;
    Bt += zb * zsB;
    if (EPI == 2) Out = (void*)((float*)Out + zb * zsO);
    else          Out = (void*)((ushort*)Out + zb * zsO);
    const int srow = lane >> 3;                 // row within 8-row staging group
    const int schunk = (lane & 7) ^ srow;       // pre-swizzled source k-chunk
    f32x4 acc[4][4] = {};
    for (int k0 = 0; k0 < CDIM; k0 += 64) {
        __syncthreads();
#pragma unroll
        for (int c = 0; c < 8; ++c) {
            const int r = (w & 1) * 64 + c * 8 + srow;
            const ushort* src = (w < 2)
                ? A  + (size_t)(row0 + r) * CDIM + k0 + schunk * 8
                : Bt + (size_t)(col0 + r) * CDIM + k0 + schunk * 8;
            gload_lds16(src, (char*)lds + w * 8192 + c * 1024);
        }
        __syncthreads();
        const int wm = (w >> 1) * 64, wn = (w & 1) * 64;
        const int lr = lane & 15, q = lane >> 4;
#pragma unroll
        for (int kk = 0; kk < 2; ++kk) {
            s16x8 af[4], bfr[4];
#pragma unroll
            for (int i = 0; i < 4; ++i) {
                const int r = wm + i * 16 + lr;
                af[i] = *(const s16x8*)&lds[r * 64 + ((((kk << 2) | q) ^ (r & 7)) << 3)];
            }
#pragma unroll
            for (int j = 0; j < 4; ++j) {
                const int r = 128 + wn + j * 16 + lr;
                bfr[j] = *(const s16x8*)&lds[r * 64 + ((((kk << 2) | q) ^ (r & 7)) << 3)];
            }
#pragma unroll
            for (int i = 0; i < 4; ++i)
#pragma unroll
                for (int j = 0; j < 4; ++j)
                    acc[i][j] = __builtin_amdgcn_mfma_f32_16x16x32_bf16(af[i], bfr[j], acc[i][j], 0, 0, 0);
        }
    }
    const int crow0 = row0 + (w >> 1) * 64;
    const int ccol0 = col0 + (w & 1) * 64;
    const int lr = (lane >> 4) * 4;
    const int lc = lane & 15;
#pragma unroll
    for (int j = 0; j < 4; ++j) {
        const int col = ccol0 + j * 16 + lc;
        const float bv = bias ? bias[col] : 0.f;
#pragma unroll
        for (int i = 0; i < 4; ++i) {
#pragma unroll
            for (int r = 0; r < 4; ++r) {
                const int row = crow0 + i * 16 + lr + r;
                if (row >= M) continue;
                const float v = acc[i][j][r] + bv;
                if (EPI == 0)
                    ((ushort*)Out)[(size_t)row * ldo + col] = f2bf(v);
                else if (EPI == 1)
                    ((ushort*)Out)[(size_t)row * ldo + col] = f2bf(gelu_f(v));
                else {
                    float* p = (float*)Out + (size_t)row * ldo + col;
                    *p = resid[(size_t)row * ldo + col] * rscale + v;
                }
            }
        }
    }
}

// ---------------- MFMA banded rel-pos attention (round-5 structure) ----------------
__global__ __launch_bounds__(256, 3) void attn_mfma(
    const ushort* __restrict__ qkv, const ushort* __restrict__ pb,
    const float* __restrict__ pos_u, const float* __restrict__ pos_v,
    ushort* __restrict__ o) {
    __shared__ __align__(16) char smem[50176];
    ushort* Kl   = (ushort*)smem;               // [176][72]
    ushort* Qraw = (ushort*)(smem + 25344);     // [64][72]
    ushort* Bd   = (ushort*)(smem + 34560);     // [4][16][104]
    ushort* Pl   = (ushort*)smem;               // phase2: [64][200]
    ushort* Vsub = (ushort*)(smem + 25600);     // phase2: [4 d0][192 j][16 d]

    const int tid = threadIdx.x;
    const int w = tid >> 6, lane = tid & 63;
    const int t0 = blockIdx.x * 64;
    const int h = blockIdx.y, b = blockIdx.z;

    // ---- stage Qraw ----
    {
        const int row = tid >> 2, c = (tid & 3) << 4;
        int t = t0 + row; t = (t < TSEQ) ? t : TSEQ - 1;
        const ushort* qp = qkv + (size_t)(b * TSEQ + t) * QKVDIM + h * DKK + c;
        *(s16x8*)&Qraw[row * 72 + c]     = *(const s16x8*)qp;
        *(s16x8*)&Qraw[row * 72 + c + 8] = *(const s16x8*)(qp + 8);
    }
    // ---- stage K ----
    for (int task = tid; task < NS * 4; task += 256) {
        const int j = task >> 2, c = (task & 3) << 4;
        int kb = t0 - HALFW + j; kb = kb < 0 ? 0 : (kb < TSEQ ? kb : TSEQ - 1);
        const ushort* kp = qkv + (size_t)(b * TSEQ + kb) * QKVDIM + CDIM + h * DKK + c;
        *(s16x8*)&Kl[j * 72 + c]     = *(const s16x8*)kp;
        *(s16x8*)&Kl[j * 72 + c + 8] = *(const s16x8*)(kp + 8);
    }
    __syncthreads();

    const int m0 = w * 16;
    const int lr = lane & 15, lk = (lane >> 4) * 8;
    const f32x4 zero = {0.f, 0.f, 0.f, 0.f};

    // ---- rel-pos B-fragments straight from global (L2-hot, 14 KB/head) ----
    const ushort* pbh = pb + (size_t)949 * CDIM + h * DKK;
    s16x8 pfr[7][2];
#pragma unroll
    for (int uf = 0; uf < 7; ++uf) {
        pfr[uf][0] = *(const s16x8*)&pbh[(size_t)(uf * 16 + lr) * CDIM + lk];
        pfr[uf][1] = *(const s16x8*)&pbh[(size_t)(uf * 16 + lr) * CDIM + 32 + lk];
    }

    // ---- build qu/qv fragments in regs ----
    s16x8 qr0 = *(const s16x8*)&Qraw[(m0 + lr) * 72 + lk];
    s16x8 qr1 = *(const s16x8*)&Qraw[(m0 + lr) * 72 + 32 + lk];
    s16x8 qu0, qu1, qv0, qv1;
#pragma unroll
    for (int e = 0; e < 8; ++e) {
        const float q0 = bf2f((ushort)qr0[e]), q1 = bf2f((ushort)qr1[e]);
        qu0[e] = (short)f2bf(q0 + pos_u[h * DKK + lk + e]);
        qu1[e] = (short)f2bf(q1 + pos_u[h * DKK + 32 + lk + e]);
        qv0[e] = (short)f2bf(q0 + pos_v[h * DKK + lk + e]);
        qv1[e] = (short)f2bf(q1 + pos_v[h * DKK + 32 + lk + e]);
    }

    // ---- score MFMAs ----
    f32x4 acS[11], acB[7];
    __builtin_amdgcn_s_setprio(1);
#pragma unroll
    for (int uf = 0; uf < 7; ++uf) {
        acB[uf] = __builtin_amdgcn_mfma_f32_16x16x32_bf16(qv0, pfr[uf][0], zero, 0, 0, 0);
        acB[uf] = __builtin_amdgcn_mfma_f32_16x16x32_bf16(qv1, pfr[uf][1], acB[uf], 0, 0, 0);
    }
#pragma unroll
    for (int jf = 0; jf < 11; ++jf) {
        s16x8 k0 = *(const s16x8*)&Kl[(jf * 16 + lr) * 72 + lk];
        s16x8 k1 = *(const s16x8*)&Kl[(jf * 16 + lr) * 72 + 32 + lk];
        acS[jf] = __builtin_amdgcn_mfma_f32_16x16x32_bf16(qu0, k0, zero, 0, 0, 0);
        acS[jf] = __builtin_amdgcn_mfma_f32_16x16x32_bf16(qu1, k1, acS[jf], 0, 0, 0);
    }
    __builtin_amdgcn_s_setprio(0);

    // ---- bd -> LDS (own-wave region) ----
    ushort* bdw = Bd + w * 16 * 104;
#pragma unroll
    for (int uf = 0; uf < 7; ++uf)
#pragma unroll
        for (int r = 0; r < 4; ++r)
            bdw[((lane >> 4) * 4 + r) * 104 + uf * 16 + lr] = f2bf(acB[uf][r]);
    // ---- combine + masked softmax (deferred 1/sum) ----
    float mx[4] = {-1e30f, -1e30f, -1e30f, -1e30f};
#pragma unroll
    for (int jf = 0; jf < 11; ++jf)
#pragma unroll
        for (int r = 0; r < 4; ++r) {
            const int tl = (lane >> 4) * 4 + r;
            const int tloc = m0 + tl;
            const int j = jf * 16 + lr;
            const int u = j - tloc;
            const int s = t0 - HALFW + j;
            const bool valid = (u >= 0) & (u <= 2 * HALFW) & (s >= 0) & (s < TSEQ)
                               & (t0 + tloc < TSEQ);
            float sc = -1e30f;
            if (valid) sc = (acS[jf][r] + bf2f(bdw[tl * 104 + u])) * 0.125f;
            acS[jf][r] = sc;
            mx[r] = fmaxf(mx[r], sc);
        }
#pragma unroll
    for (int r = 0; r < 4; ++r)
#pragma unroll
        for (int off = 8; off; off >>= 1)
            mx[r] = fmaxf(mx[r], __shfl_xor(mx[r], off));
    float sm[4] = {0.f, 0.f, 0.f, 0.f};
#pragma unroll
    for (int jf = 0; jf < 11; ++jf)
#pragma unroll
        for (int r = 0; r < 4; ++r) {
            float e = __expf(acS[jf][r] - mx[r]);
            acS[jf][r] = e;
            sm[r] += e;
        }
#pragma unroll
    for (int r = 0; r < 4; ++r) {
#pragma unroll
        for (int off = 8; off; off >>= 1) sm[r] += __shfl_xor(sm[r], off);
        sm[r] = 1.f / sm[r];
    }
    __syncthreads();   // all waves done reading Kl/Qraw & own Bd

    // ---- write P (A-frag layout) + zero pad cols [176,192) ----
#pragma unroll
    for (int jf = 0; jf < 11; ++jf)
#pragma unroll
        for (int r = 0; r < 4; ++r)
            Pl[(m0 + (lane >> 4) * 4 + r) * 200 + jf * 16 + lr] = f2bf(acS[jf][r]);
#pragma unroll
    for (int r = 0; r < 4; ++r)
        Pl[(m0 + (lane >> 4) * 4 + r) * 200 + 176 + lr] = 0;

    // ---- stage V row-major, d0-subtiled [4][192][16] via global_load_lds ----
    for (int sp = w; sp < 24; sp += 4) {
        const int ob = sp * 1024 + lane * 16;
        const int d0c = ob / 6144;
        const int rem = ob - d0c * 6144;
        const int j = rem >> 5;
        const int halfo = (rem & 31) >> 4;
        int t = t0 - HALFW + j; t = t < 0 ? 0 : (t < TSEQ ? t : TSEQ - 1);
        const ushort* src = qkv + (size_t)(b * TSEQ + t) * QKVDIM + 2 * CDIM
                            + h * DKK + d0c * 16 + halfo * 8;
        gload_lds16(src, (char*)Vsub + sp * 1024);
    }
    __syncthreads();

    // ---- PV: B-frags via ds_read_b64_tr_b16 ----
    s16x8 pa[6];
#pragma unroll
    for (int ks = 0; ks < 6; ++ks)
        pa[ks] = *(const s16x8*)&Pl[(m0 + lr) * 200 + ks * 32 + lk];
    const unsigned vbase = LDSOFF(Vsub);
    f32x4 acO[4] = {};
#pragma unroll
    for (int nf = 0; nf < 4; ++nf) {
        const unsigned abase = vbase + nf * 6144 + ((lane >> 4) << 8) + ((lane & 15) << 1);
        s16x4 lo[6], hi[6];
#pragma unroll
        for (int ks = 0; ks < 6; ++ks) {
            lo[ks] = tr_read(abase + ks * 1024);
            hi[ks] = tr_read128(abase + ks * 1024);
        }
        asm volatile("s_waitcnt lgkmcnt(0)" ::: "memory");
        __builtin_amdgcn_sched_barrier(0);
        __builtin_amdgcn_s_setprio(1);
#pragma unroll
        for (int ks = 0; ks < 6; ++ks) {
            s16x8 vb = __builtin_shufflevector(lo[ks], hi[ks], 0, 1, 2, 3, 4, 5, 6, 7);
            acO[nf] = __builtin_amdgcn_mfma_f32_16x16x32_bf16(pa[ks], vb, acO[nf], 0, 0, 0);
        }
        __builtin_amdgcn_s_setprio(0);
    }
#pragma unroll
    for (int nf = 0; nf < 4; ++nf)
#pragma unroll
        for (int r = 0; r < 4; ++r) {
            const int t = t0 + m0 + (lane >> 4) * 4 + r;
            if (t < TSEQ)
                o[(size_t)(b * TSEQ + t) * CDIM + h * DKK + nf * 16 + lr] =
                    f2bf(acO[nf][r] * sm[r]);
        }
}

// ---------------- launch ----------------
extern "C" void kernel_launch(void* const* d_in, const int* in_sizes, int n_in,
                              void* d_out, int out_size, void* d_ws, size_t ws_size,
                              hipStream_t stream) {
    const float* x     = (const float*)d_in[0];
    const float* Wq    = (const float*)d_in[1];
    const float* bq    = (const float*)d_in[2];
    const float* Wk    = (const float*)d_in[3];
    const float* bk    = (const float*)d_in[4];
    const float* Wv    = (const float*)d_in[5];
    const float* bv    = (const float*)d_in[6];
    const float* Wo    = (const float*)d_in[7];
    const float* bo    = (const float*)d_in[8];
    const float* Wp    = (const float*)d_in[9];
    const float* pos_u = (const float*)d_in[10];
    const float* pos_v = (const float*)d_in[11];
    const float* ln1g  = (const float*)d_in[12];
    const float* ln1b  = (const float*)d_in[13];
    const float* ln2g  = (const float*)d_in[14];
    const float* ln2b  = (const float*)d_in[15];
    const float* W1    = (const float*)d_in[16];
    const float* b1    = (const float*)d_in[17];
    const float* W2    = (const float*)d_in[18];
    const float* b2    = (const float*)d_in[19];

    float* h = (float*)d_out;
    const float XS = 27.712812921102035f;   // sqrt(768)

    char* p = (char*)d_ws;
    ushort* Wtqkv = (ushort*)p;               p += (size_t)LNUM * QKVDIM * CDIM * 2;
    ushort* Wtp   = (ushort*)p;               p += (size_t)LNUM * CDIM * CDIM * 2;
    ushort* Wto   = (ushort*)p;               p += (size_t)LNUM * CDIM * CDIM * 2;
    ushort* Wt1   = (ushort*)p;               p += (size_t)LNUM * CDIM * CDIM * 2;
    ushort* Wt2   = (ushort*)p;               p += (size_t)LNUM * CDIM * CDIM * 2;
    float*  bqkv  = (float*)p;                p += (size_t)LNUM * QKVDIM * 4;
    ushort* pe    = (ushort*)p;               p += (size_t)2048 * CDIM * 2;
    ushort* pb    = (ushort*)p;               p += (size_t)LNUM * 2048 * CDIM * 2;
    ushort* y     = (ushort*)p;               p += (size_t)MPAD * CDIM * 2;
    ushort* qkv   = (ushort*)p;               p += (size_t)MPAD * QKVDIM * 2;
    ushort* o     = (ushort*)p;               p += (size_t)MPAD * CDIM * 2;
    ushort* hid   = (ushort*)p;               p += (size_t)MPAD * CDIM * 2;

    transpose_pack<<<dim3(24, 24, LNUM * 7), dim3(32, 8), 0, stream>>>(
        Wq, Wk, Wv, Wp, Wo, W1, W2, Wtqkv, Wtp, Wto, Wt1, Wt2);
    prep_small<<<384, 256, 0, stream>>>(pe, bq, bk, bv, bqkv);

    const dim3 gQKV(32, QKVDIM / 128);
    const dim3 gC(32, CDIM / 128);
    const dim3 gP(2, CDIM / 128, LNUM);     // both layers' P-projections in one dispatch
    const dim3 gA(16, HHEADS, BBATCH);

    gemm_mfma<0><<<gP, 256, 0, stream>>>(pe + (size_t)896 * CDIM, Wtp, nullptr,
                                         pb + (size_t)896 * CDIM, 256, CDIM,
                                         nullptr, 0.f,
                                         (size_t)CDIM * CDIM, (size_t)2048 * CDIM);

    for (int l = 0; l < LNUM; ++l) {
        const size_t wo = (size_t)l * CDIM * CDIM;
        const float* res1 = (l == 0) ? x : h;
        const float rs1   = (l == 0) ? XS : 1.f;
        ln_kernel<<<MROWS, 192, 0, stream>>>(res1, ln1g + l * CDIM, ln1b + l * CDIM, y, rs1);
        gemm_mfma<0><<<gQKV, 256, 0, stream>>>(y, Wtqkv + (size_t)l * QKVDIM * CDIM,
                                               bqkv + l * QKVDIM, qkv, MROWS, QKVDIM,
                                               nullptr, 0.f, 0, 0);
        attn_mfma<<<gA, 256, 0, stream>>>(
            qkv, pb + (size_t)l * 2048 * CDIM,
            pos_u + l * HHEADS * DKK, pos_v + l * HHEADS * DKK, o);
        gemm_mfma<2><<<gC, 256, 0, stream>>>(o, Wto + wo, bo + l * CDIM, h, MROWS, CDIM,
                                             res1, rs1, 0, 0);
        ln_kernel<<<MROWS, 192, 0, stream>>>(h, ln2g + l * CDIM, ln2b + l * CDIM, y, 1.f);
        gemm_mfma<1><<<gC, 256, 0, stream>>>(y, Wt1 + wo, b1 + l * CDIM, hid, MROWS, CDIM,
                                             nullptr, 0.f, 0, 0);
        gemm_mfma<2><<<gC, 256, 0, stream>>>(hid, Wt2 + wo, b2 + l * CDIM, h, MROWS, CDIM,
                                             h, 1.f, 0, 0);
    }
}

// Round 7
// 262.014 us; speedup vs baseline: 7.9940x; 1.2538x over previous
//
#include <hip/hip_runtime.h>
#include <math.h>

#define LNUM 2
#define BBATCH 4
#define TSEQ 1000
#define CDIM 768
#define HHEADS 12
#define DKK 64
#define PPOS (2*TSEQ-1)   // 1999
#define HALFW 50
#define MROWS (BBATCH*TSEQ)     // 4000
#define MPAD 4096
#define QKVDIM (3*CDIM)         // 2304
#define NS 176                  // real key span per 64-query tile (padded to 192)

typedef __attribute__((ext_vector_type(8))) short s16x8;
typedef __attribute__((ext_vector_type(4))) short s16x4;
typedef __attribute__((ext_vector_type(4))) float f32x4;

#define LDSOFF(p) ((unsigned)(uintptr_t)(__attribute__((address_space(3))) const void*)(p))

__device__ __forceinline__ ushort f2bf(float x) {
    unsigned u = __float_as_uint(x);
    unsigned r = u + 0x7FFFu + ((u >> 16) & 1u);
    return (ushort)(r >> 16);
}
__device__ __forceinline__ float bf2f(ushort h) {
    return __uint_as_float(((unsigned)h) << 16);
}
__device__ __forceinline__ float gelu_f(float x) {
    float u = 0.7978845608028654f * (x + 0.044715f * x * x * x);
    return 0.5f * x * (1.f + tanhf(u));
}
__device__ __forceinline__ void gload_lds16(const void* g, void* l) {
    __builtin_amdgcn_global_load_lds(
        (const __attribute__((address_space(1))) void*)g,
        (__attribute__((address_space(3))) void*)l, 16, 0, 0);
}
__device__ __forceinline__ s16x4 tr_read(unsigned addr) {
    s16x4 d;
    asm volatile("ds_read_b64_tr_b16 %0, %1" : "=v"(d) : "v"(addr));
    return d;
}
__device__ __forceinline__ s16x4 tr_read128(unsigned addr) {
    s16x4 d;
    asm volatile("ds_read_b64_tr_b16 %0, %1 offset:128" : "=v"(d) : "v"(addr));
    return d;
}

// ---------------- weight transpose + bf16 convert ----------------
__global__ __launch_bounds__(256) void transpose_pack(
    const float* __restrict__ Wq, const float* __restrict__ Wk,
    const float* __restrict__ Wv, const float* __restrict__ Wp,
    const float* __restrict__ Wo, const float* __restrict__ W1,
    const float* __restrict__ W2,
    ushort* __restrict__ Wtqkv, ushort* __restrict__ Wtp,
    ushort* __restrict__ Wto, ushort* __restrict__ Wt1, ushort* __restrict__ Wt2) {
    const int l = blockIdx.z / 7, m = blockIdx.z % 7;
    const float* srcs[7] = {Wq, Wk, Wv, Wp, Wo, W1, W2};
    const float* src = srcs[m] + (size_t)l * CDIM * CDIM;
    ushort* dst;
    if (m < 3)       dst = Wtqkv + (size_t)l * QKVDIM * CDIM + (size_t)m * CDIM * CDIM;
    else if (m == 3) dst = Wtp + (size_t)l * CDIM * CDIM;
    else if (m == 4) dst = Wto + (size_t)l * CDIM * CDIM;
    else if (m == 5) dst = Wt1 + (size_t)l * CDIM * CDIM;
    else             dst = Wt2 + (size_t)l * CDIM * CDIM;
    __shared__ float tile[32][33];
    const int tx = threadIdx.x, ty = threadIdx.y;       // (32, 8)
    const int c0 = blockIdx.x * 32, r0 = blockIdx.y * 32;
#pragma unroll
    for (int i = 0; i < 4; ++i)
        tile[ty + i * 8][tx] = src[(size_t)(r0 + ty + i * 8) * CDIM + c0 + tx];
    __syncthreads();
#pragma unroll
    for (int i = 0; i < 4; ++i)
        dst[(size_t)(c0 + ty + i * 8) * CDIM + r0 + tx] = f2bf(tile[tx][ty + i * 8]);
}

// ---------------- fused small prep: pos-enc rows [896,1152) + qkv bias pack ----------------
__global__ __launch_bounds__(256) void prep_small(ushort* __restrict__ pe,
                                                  const float* __restrict__ bq,
                                                  const float* __restrict__ bk,
                                                  const float* __restrict__ bv,
                                                  float* __restrict__ bqkv) {
    int idx = blockIdx.x * 256 + threadIdx.x;
    const int npair = 256 * (CDIM / 2);
    if (idx < npair) {
        int jloc = idx / (CDIM / 2);
        int m = idx - jloc * (CDIM / 2);
        int j = 896 + jloc;
        float rel = (float)(TSEQ - 1 - j);
        float div = expf(-(float)(2 * m) * (9.210340371976184f / (float)CDIM));
        float a = rel * div;
        pe[(size_t)j * CDIM + 2 * m]     = f2bf(sinf(a));
        pe[(size_t)j * CDIM + 2 * m + 1] = f2bf(cosf(a));
    }
    if (idx < LNUM * QKVDIM) {
        int l = idx / QKVDIM, c = idx - l * QKVDIM;
        float v;
        if (c < CDIM)            v = bq[l * CDIM + c];
        else if (c < 2 * CDIM)   v = bk[l * CDIM + c - CDIM];
        else                     v = bv[l * CDIM + c - 2 * CDIM];
        bqkv[idx] = v;
    }
}

// ---------------- LayerNorm: f32 in (xscale-on-load), bf16 out; 192 thr, float4 ----------------
__global__ __launch_bounds__(192) void ln_kernel(const float* __restrict__ in,
                                                 const float* __restrict__ g,
                                                 const float* __restrict__ bta,
                                                 ushort* __restrict__ y, float xscale) {
    const int row = blockIdx.x, tid = threadIdx.x;
    float4 v = *(const float4*)&in[(size_t)row * CDIM + tid * 4];
    v.x *= xscale; v.y *= xscale; v.z *= xscale; v.w *= xscale;
    float s  = v.x + v.y + v.z + v.w;
    float ss = v.x * v.x + v.y * v.y + v.z * v.z + v.w * v.w;
#pragma unroll
    for (int off = 32; off; off >>= 1) {
        s  += __shfl_xor(s, off);
        ss += __shfl_xor(ss, off);
    }
    __shared__ float sm[3], sq[3];
    const int wid = tid >> 6, lane = tid & 63;
    if (lane == 0) { sm[wid] = s; sq[wid] = ss; }
    __syncthreads();
    const float st  = sm[0] + sm[1] + sm[2];
    const float sst = sq[0] + sq[1] + sq[2];
    const float mean = st * (1.f / CDIM);
    const float var  = sst * (1.f / CDIM) - mean * mean;
    const float rstd = rsqrtf(var + 1e-5f);
    const float4 g4 = *(const float4*)&g[tid * 4];
    const float4 b4 = *(const float4*)&bta[tid * 4];
    ushort o0 = f2bf((v.x - mean) * rstd * g4.x + b4.x);
    ushort o1 = f2bf((v.y - mean) * rstd * g4.y + b4.y);
    ushort o2 = f2bf((v.z - mean) * rstd * g4.z + b4.z);
    ushort o3 = f2bf((v.w - mean) * rstd * g4.w + b4.w);
    uint2 pk; pk.x = (unsigned)o0 | ((unsigned)o1 << 16);
    pk.y = (unsigned)o2 | ((unsigned)o3 << 16);
    *(uint2*)&y[(size_t)row * CDIM + tid * 4] = pk;
}

// ---------------- MFMA bf16 GEMM: 64x128 tile, BK=64, double-buffered LDS ----------------
// LDS per buffer: [192 rows][64 k] (A rows 0-63, B rows 64-191), row stride 128 B,
// logical k-chunk c of row r at slot c ^ (r&7) (bijective swizzle, source-side
// pre-permuted so global_load_lds dest stays linear). One barrier per k-step:
// STAGE(next) issued before compute(cur) -> load latency hidden under MFMA.
// EPI 0: bf16 store; 1: gelu->bf16 store; 2: Out(f32) = resid*rscale + acc + bias
template <int EPI>
__global__ __launch_bounds__(256, 3) void gemm64(const ushort* __restrict__ A,
                                                 const ushort* __restrict__ Bt,
                                                 const float* __restrict__ bias,
                                                 void* Out, int M, int ldo,
                                                 const float* resid, float rscale,
                                                 size_t zsB, size_t zsO) {
    __shared__ ushort lds[24576];              // 2 x 24 KB
    const int tid = threadIdx.x;
    const int w = tid >> 6, lane = tid & 63;
    const int row0 = blockIdx.x * 64, col0 = blockIdx.y * 128;
    const size_t zb = blockIdx.z;
    Bt += zb * zsB;
    if (EPI == 2) Out = (void*)((float*)Out + zb * zsO);
    else          Out = (void*)((ushort*)Out + zb * zsO);

    const int srow8  = lane >> 3;              // row within 8-row staging group
    const int schunk = (lane & 7) ^ srow8;     // pre-swizzled source k-chunk

#define STAGE64(buf, k0)                                                        \
    {                                                                           \
        _Pragma("unroll")                                                       \
        for (int g = 0; g < 6; ++g) {                                           \
            const int grp = w * 6 + g;                                          \
            const int r = grp * 8 + srow8;                                      \
            const ushort* src = (grp < 8)                                       \
                ? A  + (size_t)(row0 + r) * CDIM + (k0) + schunk * 8            \
                : Bt + (size_t)(col0 + (r - 64)) * CDIM + (k0) + schunk * 8;    \
            gload_lds16(src, (char*)lds + (buf) * 24576 + grp * 1024);          \
        }                                                                       \
    }

    const int wm = (w >> 1) * 32, wn = (w & 1) * 64;
    const int lr = lane & 15, q = lane >> 4;
    f32x4 acc[2][4] = {};

    STAGE64(0, 0);
    __syncthreads();
    int cur = 0;
    for (int k0 = 0; k0 < CDIM; k0 += 64) {
        if (k0 + 64 < CDIM) STAGE64(cur ^ 1, k0 + 64);
        const int base = cur * 12288;
#pragma unroll
        for (int kk = 0; kk < 2; ++kk) {
            s16x8 af[2], bfr[4];
#pragma unroll
            for (int i = 0; i < 2; ++i) {
                const int r = wm + i * 16 + lr;
                af[i] = *(const s16x8*)&lds[base + r * 64 + ((((kk << 2) | q) ^ (r & 7)) << 3)];
            }
#pragma unroll
            for (int j = 0; j < 4; ++j) {
                const int r = 64 + wn + j * 16 + lr;
                bfr[j] = *(const s16x8*)&lds[base + r * 64 + ((((kk << 2) | q) ^ (r & 7)) << 3)];
            }
#pragma unroll
            for (int i = 0; i < 2; ++i)
#pragma unroll
                for (int j = 0; j < 4; ++j)
                    acc[i][j] = __builtin_amdgcn_mfma_f32_16x16x32_bf16(af[i], bfr[j], acc[i][j], 0, 0, 0);
        }
        __syncthreads();
        cur ^= 1;
    }
#undef STAGE64

    const int lrr = (lane >> 4) * 4;
    const int lc = lane & 15;
#pragma unroll
    for (int j = 0; j < 4; ++j) {
        const int col = col0 + wn + j * 16 + lc;
        const float bv = bias ? bias[col] : 0.f;
#pragma unroll
        for (int i = 0; i < 2; ++i) {
#pragma unroll
            for (int r = 0; r < 4; ++r) {
                const int row = row0 + wm + i * 16 + lrr + r;
                if (row >= M) continue;
                const float v = acc[i][j][r] + bv;
                if (EPI == 0)
                    ((ushort*)Out)[(size_t)row * ldo + col] = f2bf(v);
                else if (EPI == 1)
                    ((ushort*)Out)[(size_t)row * ldo + col] = f2bf(gelu_f(v));
                else {
                    float* p = (float*)Out + (size_t)row * ldo + col;
                    *p = resid[(size_t)row * ldo + col] * rscale + v;
                }
            }
        }
    }
}

// ---------------- MFMA banded rel-pos attention (round-5 structure) ----------------
__global__ __launch_bounds__(256, 3) void attn_mfma(
    const ushort* __restrict__ qkv, const ushort* __restrict__ pb,
    const float* __restrict__ pos_u, const float* __restrict__ pos_v,
    ushort* __restrict__ o) {
    __shared__ __align__(16) char smem[50176];
    ushort* Kl   = (ushort*)smem;               // [176][72]
    ushort* Qraw = (ushort*)(smem + 25344);     // [64][72]
    ushort* Bd   = (ushort*)(smem + 34560);     // [4][16][104]
    ushort* Pl   = (ushort*)smem;               // phase2: [64][200]
    ushort* Vsub = (ushort*)(smem + 25600);     // phase2: [4 d0][192 j][16 d]

    const int tid = threadIdx.x;
    const int w = tid >> 6, lane = tid & 63;
    const int t0 = blockIdx.x * 64;
    const int h = blockIdx.y, b = blockIdx.z;

    // ---- stage Qraw ----
    {
        const int row = tid >> 2, c = (tid & 3) << 4;
        int t = t0 + row; t = (t < TSEQ) ? t : TSEQ - 1;
        const ushort* qp = qkv + (size_t)(b * TSEQ + t) * QKVDIM + h * DKK + c;
        *(s16x8*)&Qraw[row * 72 + c]     = *(const s16x8*)qp;
        *(s16x8*)&Qraw[row * 72 + c + 8] = *(const s16x8*)(qp + 8);
    }
    // ---- stage K ----
    for (int task = tid; task < NS * 4; task += 256) {
        const int j = task >> 2, c = (task & 3) << 4;
        int kb = t0 - HALFW + j; kb = kb < 0 ? 0 : (kb < TSEQ ? kb : TSEQ - 1);
        const ushort* kp = qkv + (size_t)(b * TSEQ + kb) * QKVDIM + CDIM + h * DKK + c;
        *(s16x8*)&Kl[j * 72 + c]     = *(const s16x8*)kp;
        *(s16x8*)&Kl[j * 72 + c + 8] = *(const s16x8*)(kp + 8);
    }
    __syncthreads();

    const int m0 = w * 16;
    const int lr = lane & 15, lk = (lane >> 4) * 8;
    const f32x4 zero = {0.f, 0.f, 0.f, 0.f};

    // ---- rel-pos B-fragments straight from global (L2-hot, 14 KB/head) ----
    const ushort* pbh = pb + (size_t)949 * CDIM + h * DKK;
    s16x8 pfr[7][2];
#pragma unroll
    for (int uf = 0; uf < 7; ++uf) {
        pfr[uf][0] = *(const s16x8*)&pbh[(size_t)(uf * 16 + lr) * CDIM + lk];
        pfr[uf][1] = *(const s16x8*)&pbh[(size_t)(uf * 16 + lr) * CDIM + 32 + lk];
    }

    // ---- build qu/qv fragments in regs ----
    s16x8 qr0 = *(const s16x8*)&Qraw[(m0 + lr) * 72 + lk];
    s16x8 qr1 = *(const s16x8*)&Qraw[(m0 + lr) * 72 + 32 + lk];
    s16x8 qu0, qu1, qv0, qv1;
#pragma unroll
    for (int e = 0; e < 8; ++e) {
        const float q0 = bf2f((ushort)qr0[e]), q1 = bf2f((ushort)qr1[e]);
        qu0[e] = (short)f2bf(q0 + pos_u[h * DKK + lk + e]);
        qu1[e] = (short)f2bf(q1 + pos_u[h * DKK + 32 + lk + e]);
        qv0[e] = (short)f2bf(q0 + pos_v[h * DKK + lk + e]);
        qv1[e] = (short)f2bf(q1 + pos_v[h * DKK + 32 + lk + e]);
    }

    // ---- score MFMAs ----
    f32x4 acS[11], acB[7];
    __builtin_amdgcn_s_setprio(1);
#pragma unroll
    for (int uf = 0; uf < 7; ++uf) {
        acB[uf] = __builtin_amdgcn_mfma_f32_16x16x32_bf16(qv0, pfr[uf][0], zero, 0, 0, 0);
        acB[uf] = __builtin_amdgcn_mfma_f32_16x16x32_bf16(qv1, pfr[uf][1], acB[uf], 0, 0, 0);
    }
#pragma unroll
    for (int jf = 0; jf < 11; ++jf) {
        s16x8 k0 = *(const s16x8*)&Kl[(jf * 16 + lr) * 72 + lk];
        s16x8 k1 = *(const s16x8*)&Kl[(jf * 16 + lr) * 72 + 32 + lk];
        acS[jf] = __builtin_amdgcn_mfma_f32_16x16x32_bf16(qu0, k0, zero, 0, 0, 0);
        acS[jf] = __builtin_amdgcn_mfma_f32_16x16x32_bf16(qu1, k1, acS[jf], 0, 0, 0);
    }
    __builtin_amdgcn_s_setprio(0);

    // ---- bd -> LDS (own-wave region) ----
    ushort* bdw = Bd + w * 16 * 104;
#pragma unroll
    for (int uf = 0; uf < 7; ++uf)
#pragma unroll
        for (int r = 0; r < 4; ++r)
            bdw[((lane >> 4) * 4 + r) * 104 + uf * 16 + lr] = f2bf(acB[uf][r]);
    // ---- combine + masked softmax (deferred 1/sum) ----
    float mx[4] = {-1e30f, -1e30f, -1e30f, -1e30f};
#pragma unroll
    for (int jf = 0; jf < 11; ++jf)
#pragma unroll
        for (int r = 0; r < 4; ++r) {
            const int tl = (lane >> 4) * 4 + r;
            const int tloc = m0 + tl;
            const int j = jf * 16 + lr;
            const int u = j - tloc;
            const int s = t0 - HALFW + j;
            const bool valid = (u >= 0) & (u <= 2 * HALFW) & (s >= 0) & (s < TSEQ)
                               & (t0 + tloc < TSEQ);
            float sc = -1e30f;
            if (valid) sc = (acS[jf][r] + bf2f(bdw[tl * 104 + u])) * 0.125f;
            acS[jf][r] = sc;
            mx[r] = fmaxf(mx[r], sc);
        }
#pragma unroll
    for (int r = 0; r < 4; ++r)
#pragma unroll
        for (int off = 8; off; off >>= 1)
            mx[r] = fmaxf(mx[r], __shfl_xor(mx[r], off));
    float sm[4] = {0.f, 0.f, 0.f, 0.f};
#pragma unroll
    for (int jf = 0; jf < 11; ++jf)
#pragma unroll
        for (int r = 0; r < 4; ++r) {
            float e = __expf(acS[jf][r] - mx[r]);
            acS[jf][r] = e;
            sm[r] += e;
        }
#pragma unroll
    for (int r = 0; r < 4; ++r) {
#pragma unroll
        for (int off = 8; off; off >>= 1) sm[r] += __shfl_xor(sm[r], off);
        sm[r] = 1.f / sm[r];
    }
    __syncthreads();   // all waves done reading Kl/Qraw & own Bd

    // ---- write P (A-frag layout) + zero pad cols [176,192) ----
#pragma unroll
    for (int jf = 0; jf < 11; ++jf)
#pragma unroll
        for (int r = 0; r < 4; ++r)
            Pl[(m0 + (lane >> 4) * 4 + r) * 200 + jf * 16 + lr] = f2bf(acS[jf][r]);
#pragma unroll
    for (int r = 0; r < 4; ++r)
        Pl[(m0 + (lane >> 4) * 4 + r) * 200 + 176 + lr] = 0;

    // ---- stage V row-major, d0-subtiled [4][192][16] via global_load_lds ----
    for (int sp = w; sp < 24; sp += 4) {
        const int ob = sp * 1024 + lane * 16;
        const int d0c = ob / 6144;
        const int rem = ob - d0c * 6144;
        const int j = rem >> 5;
        const int halfo = (rem & 31) >> 4;
        int t = t0 - HALFW + j; t = t < 0 ? 0 : (t < TSEQ ? t : TSEQ - 1);
        const ushort* src = qkv + (size_t)(b * TSEQ + t) * QKVDIM + 2 * CDIM
                            + h * DKK + d0c * 16 + halfo * 8;
        gload_lds16(src, (char*)Vsub + sp * 1024);
    }
    __syncthreads();

    // ---- PV: B-frags via ds_read_b64_tr_b16 ----
    s16x8 pa[6];
#pragma unroll
    for (int ks = 0; ks < 6; ++ks)
        pa[ks] = *(const s16x8*)&Pl[(m0 + lr) * 200 + ks * 32 + lk];
    const unsigned vbase = LDSOFF(Vsub);
    f32x4 acO[4] = {};
#pragma unroll
    for (int nf = 0; nf < 4; ++nf) {
        const unsigned abase = vbase + nf * 6144 + ((lane >> 4) << 8) + ((lane & 15) << 1);
        s16x4 lo[6], hi[6];
#pragma unroll
        for (int ks = 0; ks < 6; ++ks) {
            lo[ks] = tr_read(abase + ks * 1024);
            hi[ks] = tr_read128(abase + ks * 1024);
        }
        asm volatile("s_waitcnt lgkmcnt(0)" ::: "memory");
        __builtin_amdgcn_sched_barrier(0);
        __builtin_amdgcn_s_setprio(1);
#pragma unroll
        for (int ks = 0; ks < 6; ++ks) {
            s16x8 vb = __builtin_shufflevector(lo[ks], hi[ks], 0, 1, 2, 3, 4, 5, 6, 7);
            acO[nf] = __builtin_amdgcn_mfma_f32_16x16x32_bf16(pa[ks], vb, acO[nf], 0, 0, 0);
        }
        __builtin_amdgcn_s_setprio(0);
    }
#pragma unroll
    for (int nf = 0; nf < 4; ++nf)
#pragma unroll
        for (int r = 0; r < 4; ++r) {
            const int t = t0 + m0 + (lane >> 4) * 4 + r;
            if (t < TSEQ)
                o[(size_t)(b * TSEQ + t) * CDIM + h * DKK + nf * 16 + lr] =
                    f2bf(acO[nf][r] * sm[r]);
        }
}

// ---------------- launch ----------------
extern "C" void kernel_launch(void* const* d_in, const int* in_sizes, int n_in,
                              void* d_out, int out_size, void* d_ws, size_t ws_size,
                              hipStream_t stream) {
    const float* x     = (const float*)d_in[0];
    const float* Wq    = (const float*)d_in[1];
    const float* bq    = (const float*)d_in[2];
    const float* Wk    = (const float*)d_in[3];
    const float* bk    = (const float*)d_in[4];
    const float* Wv    = (const float*)d_in[5];
    const float* bv    = (const float*)d_in[6];
    const float* Wo    = (const float*)d_in[7];
    const float* bo    = (const float*)d_in[8];
    const float* Wp    = (const float*)d_in[9];
    const float* pos_u = (const float*)d_in[10];
    const float* pos_v = (const float*)d_in[11];
    const float* ln1g  = (const float*)d_in[12];
    const float* ln1b  = (const float*)d_in[13];
    const float* ln2g  = (const float*)d_in[14];
    const float* ln2b  = (const float*)d_in[15];
    const float* W1    = (const float*)d_in[16];
    const float* b1    = (const float*)d_in[17];
    const float* W2    = (const float*)d_in[18];
    const float* b2    = (const float*)d_in[19];

    float* h = (float*)d_out;
    const float XS = 27.712812921102035f;   // sqrt(768)

    char* p = (char*)d_ws;
    ushort* Wtqkv = (ushort*)p;               p += (size_t)LNUM * QKVDIM * CDIM * 2;
    ushort* Wtp   = (ushort*)p;               p += (size_t)LNUM * CDIM * CDIM * 2;
    ushort* Wto   = (ushort*)p;               p += (size_t)LNUM * CDIM * CDIM * 2;
    ushort* Wt1   = (ushort*)p;               p += (size_t)LNUM * CDIM * CDIM * 2;
    ushort* Wt2   = (ushort*)p;               p += (size_t)LNUM * CDIM * CDIM * 2;
    float*  bqkv  = (float*)p;                p += (size_t)LNUM * QKVDIM * 4;
    ushort* pe    = (ushort*)p;               p += (size_t)2048 * CDIM * 2;
    ushort* pb    = (ushort*)p;               p += (size_t)LNUM * 2048 * CDIM * 2;
    ushort* y     = (ushort*)p;               p += (size_t)MPAD * CDIM * 2;
    ushort* qkv   = (ushort*)p;               p += (size_t)MPAD * QKVDIM * 2;
    ushort* o     = (ushort*)p;               p += (size_t)MPAD * CDIM * 2;
    ushort* hid   = (ushort*)p;               p += (size_t)MPAD * CDIM * 2;

    transpose_pack<<<dim3(24, 24, LNUM * 7), dim3(32, 8), 0, stream>>>(
        Wq, Wk, Wv, Wp, Wo, W1, W2, Wtqkv, Wtp, Wto, Wt1, Wt2);
    prep_small<<<384, 256, 0, stream>>>(pe, bq, bk, bv, bqkv);

    const int MB = (MROWS + 63) / 64;        // 63 row-blocks
    const dim3 gQKV(MB, QKVDIM / 128);       // (63, 18)
    const dim3 gC(MB, CDIM / 128);           // (63, 6)
    const dim3 gP(4, CDIM / 128, LNUM);      // M=256 rel-pos rows, both layers
    const dim3 gA(16, HHEADS, BBATCH);

    gemm64<0><<<gP, 256, 0, stream>>>(pe + (size_t)896 * CDIM, Wtp, nullptr,
                                      pb + (size_t)896 * CDIM, 256, CDIM,
                                      nullptr, 0.f,
                                      (size_t)CDIM * CDIM, (size_t)2048 * CDIM);

    for (int l = 0; l < LNUM; ++l) {
        const size_t wo = (size_t)l * CDIM * CDIM;
        const float* res1 = (l == 0) ? x : h;
        const float rs1   = (l == 0) ? XS : 1.f;
        ln_kernel<<<MROWS, 192, 0, stream>>>(res1, ln1g + l * CDIM, ln1b + l * CDIM, y, rs1);
        gemm64<0><<<gQKV, 256, 0, stream>>>(y, Wtqkv + (size_t)l * QKVDIM * CDIM,
                                            bqkv + l * QKVDIM, qkv, MROWS, QKVDIM,
                                            nullptr, 0.f, 0, 0);
        attn_mfma<<<gA, 256, 0, stream>>>(
            qkv, pb + (size_t)l * 2048 * CDIM,
            pos_u + l * HHEADS * DKK, pos_v + l * HHEADS * DKK, o);
        gemm64<2><<<gC, 256, 0, stream>>>(o, Wto + wo, bo + l * CDIM, h, MROWS, CDIM,
                                          res1, rs1, 0, 0);
        ln_kernel<<<MROWS, 192, 0, stream>>>(h, ln2g + l * CDIM, ln2b + l * CDIM, y, 1.f);
        gemm64<1><<<gC, 256, 0, stream>>>(y, Wt1 + wo, b1 + l * CDIM, hid, MROWS, CDIM,
                                          nullptr, 0.f, 0, 0);
        gemm64<2><<<gC, 256, 0, stream>>>(hid, Wt2 + wo, b2 + l * CDIM, h, MROWS, CDIM,
                                          h, 1.f, 0, 0);
    }
}

// Round 8
// 261.521 us; speedup vs baseline: 8.0090x; 1.0019x over previous
//
#include <hip/hip_runtime.h>
#include <math.h>

#define LNUM 2
#define BBATCH 4
#define TSEQ 1000
#define CDIM 768
#define HHEADS 12
#define DKK 64
#define PPOS (2*TSEQ-1)   // 1999
#define HALFW 50
#define MROWS (BBATCH*TSEQ)     // 4000
#define MPAD 4096
#define QKVDIM (3*CDIM)         // 2304
#define NS 176                  // real key span per 64-query tile (padded to 192)

typedef __attribute__((ext_vector_type(8))) short s16x8;
typedef __attribute__((ext_vector_type(4))) short s16x4;
typedef __attribute__((ext_vector_type(4))) float f32x4;

#define LDSOFF(p) ((unsigned)(uintptr_t)(__attribute__((address_space(3))) const void*)(p))

__device__ __forceinline__ ushort f2bf(float x) {
    unsigned u = __float_as_uint(x);
    unsigned r = u + 0x7FFFu + ((u >> 16) & 1u);
    return (ushort)(r >> 16);
}
__device__ __forceinline__ float bf2f(ushort h) {
    return __uint_as_float(((unsigned)h) << 16);
}
__device__ __forceinline__ float gelu_f(float x) {
    float u = 0.7978845608028654f * (x + 0.044715f * x * x * x);
    return 0.5f * x * (1.f + tanhf(u));
}
__device__ __forceinline__ void gload_lds16(const void* g, void* l) {
    __builtin_amdgcn_global_load_lds(
        (const __attribute__((address_space(1))) void*)g,
        (__attribute__((address_space(3))) void*)l, 16, 0, 0);
}
__device__ __forceinline__ s16x4 tr_read(unsigned addr) {
    s16x4 d;
    asm volatile("ds_read_b64_tr_b16 %0, %1" : "=v"(d) : "v"(addr));
    return d;
}
__device__ __forceinline__ s16x4 tr_read128(unsigned addr) {
    s16x4 d;
    asm volatile("ds_read_b64_tr_b16 %0, %1 offset:128" : "=v"(d) : "v"(addr));
    return d;
}

// ---------------- weight transpose + bf16 convert ----------------
__global__ __launch_bounds__(256) void transpose_pack(
    const float* __restrict__ Wq, const float* __restrict__ Wk,
    const float* __restrict__ Wv, const float* __restrict__ Wp,
    const float* __restrict__ Wo, const float* __restrict__ W1,
    const float* __restrict__ W2,
    ushort* __restrict__ Wtqkv, ushort* __restrict__ Wtp,
    ushort* __restrict__ Wto, ushort* __restrict__ Wt1, ushort* __restrict__ Wt2) {
    const int l = blockIdx.z / 7, m = blockIdx.z % 7;
    const float* srcs[7] = {Wq, Wk, Wv, Wp, Wo, W1, W2};
    const float* src = srcs[m] + (size_t)l * CDIM * CDIM;
    ushort* dst;
    if (m < 3)       dst = Wtqkv + (size_t)l * QKVDIM * CDIM + (size_t)m * CDIM * CDIM;
    else if (m == 3) dst = Wtp + (size_t)l * CDIM * CDIM;
    else if (m == 4) dst = Wto + (size_t)l * CDIM * CDIM;
    else if (m == 5) dst = Wt1 + (size_t)l * CDIM * CDIM;
    else             dst = Wt2 + (size_t)l * CDIM * CDIM;
    __shared__ float tile[32][33];
    const int tx = threadIdx.x, ty = threadIdx.y;       // (32, 8)
    const int c0 = blockIdx.x * 32, r0 = blockIdx.y * 32;
#pragma unroll
    for (int i = 0; i < 4; ++i)
        tile[ty + i * 8][tx] = src[(size_t)(r0 + ty + i * 8) * CDIM + c0 + tx];
    __syncthreads();
#pragma unroll
    for (int i = 0; i < 4; ++i)
        dst[(size_t)(c0 + ty + i * 8) * CDIM + r0 + tx] = f2bf(tile[tx][ty + i * 8]);
}

// ---------------- fused small prep: pos-enc rows [896,1152) + qkv bias pack ----------------
__global__ __launch_bounds__(256) void prep_small(ushort* __restrict__ pe,
                                                  const float* __restrict__ bq,
                                                  const float* __restrict__ bk,
                                                  const float* __restrict__ bv,
                                                  float* __restrict__ bqkv) {
    int idx = blockIdx.x * 256 + threadIdx.x;
    const int npair = 256 * (CDIM / 2);
    if (idx < npair) {
        int jloc = idx / (CDIM / 2);
        int m = idx - jloc * (CDIM / 2);
        int j = 896 + jloc;
        float rel = (float)(TSEQ - 1 - j);
        float div = expf(-(float)(2 * m) * (9.210340371976184f / (float)CDIM));
        float a = rel * div;
        pe[(size_t)j * CDIM + 2 * m]     = f2bf(sinf(a));
        pe[(size_t)j * CDIM + 2 * m + 1] = f2bf(cosf(a));
    }
    if (idx < LNUM * QKVDIM) {
        int l = idx / QKVDIM, c = idx - l * QKVDIM;
        float v;
        if (c < CDIM)            v = bq[l * CDIM + c];
        else if (c < 2 * CDIM)   v = bk[l * CDIM + c - CDIM];
        else                     v = bv[l * CDIM + c - 2 * CDIM];
        bqkv[idx] = v;
    }
}

// ---------------- LayerNorm: f32 in (xscale-on-load), bf16 out; 192 thr, float4 ----------------
__global__ __launch_bounds__(192) void ln_kernel(const float* __restrict__ in,
                                                 const float* __restrict__ g,
                                                 const float* __restrict__ bta,
                                                 ushort* __restrict__ y, float xscale) {
    const int row = blockIdx.x, tid = threadIdx.x;
    float4 v = *(const float4*)&in[(size_t)row * CDIM + tid * 4];
    v.x *= xscale; v.y *= xscale; v.z *= xscale; v.w *= xscale;
    float s  = v.x + v.y + v.z + v.w;
    float ss = v.x * v.x + v.y * v.y + v.z * v.z + v.w * v.w;
#pragma unroll
    for (int off = 32; off; off >>= 1) {
        s  += __shfl_xor(s, off);
        ss += __shfl_xor(ss, off);
    }
    __shared__ float sm[3], sq[3];
    const int wid = tid >> 6, lane = tid & 63;
    if (lane == 0) { sm[wid] = s; sq[wid] = ss; }
    __syncthreads();
    const float st  = sm[0] + sm[1] + sm[2];
    const float sst = sq[0] + sq[1] + sq[2];
    const float mean = st * (1.f / CDIM);
    const float var  = sst * (1.f / CDIM) - mean * mean;
    const float rstd = rsqrtf(var + 1e-5f);
    const float4 g4 = *(const float4*)&g[tid * 4];
    const float4 b4 = *(const float4*)&bta[tid * 4];
    ushort o0 = f2bf((v.x - mean) * rstd * g4.x + b4.x);
    ushort o1 = f2bf((v.y - mean) * rstd * g4.y + b4.y);
    ushort o2 = f2bf((v.z - mean) * rstd * g4.z + b4.z);
    ushort o3 = f2bf((v.w - mean) * rstd * g4.w + b4.w);
    uint2 pk; pk.x = (unsigned)o0 | ((unsigned)o1 << 16);
    pk.y = (unsigned)o2 | ((unsigned)o3 << 16);
    *(uint2*)&y[(size_t)row * CDIM + tid * 4] = pk;
}

// ---------------- MFMA bf16 GEMM: 64x128 tile, BK=64, double-buffered LDS ----------------
// (unchanged from round 7)
template <int EPI>
__global__ __launch_bounds__(256, 3) void gemm64(const ushort* __restrict__ A,
                                                 const ushort* __restrict__ Bt,
                                                 const float* __restrict__ bias,
                                                 void* Out, int M, int ldo,
                                                 const float* resid, float rscale,
                                                 size_t zsB, size_t zsO) {
    __shared__ ushort lds[24576];              // 2 x 24 KB
    const int tid = threadIdx.x;
    const int w = tid >> 6, lane = tid & 63;
    const int row0 = blockIdx.x * 64, col0 = blockIdx.y * 128;
    const size_t zb = blockIdx.z;
    Bt += zb * zsB;
    if (EPI == 2) Out = (void*)((float*)Out + zb * zsO);
    else          Out = (void*)((ushort*)Out + zb * zsO);

    const int srow8  = lane >> 3;
    const int schunk = (lane & 7) ^ srow8;

#define STAGE64(buf, k0)                                                        \
    {                                                                           \
        _Pragma("unroll")                                                       \
        for (int g = 0; g < 6; ++g) {                                           \
            const int grp = w * 6 + g;                                          \
            const int r = grp * 8 + srow8;                                      \
            const ushort* src = (grp < 8)                                       \
                ? A  + (size_t)(row0 + r) * CDIM + (k0) + schunk * 8            \
                : Bt + (size_t)(col0 + (r - 64)) * CDIM + (k0) + schunk * 8;    \
            gload_lds16(src, (char*)lds + (buf) * 24576 + grp * 1024);          \
        }                                                                       \
    }

    const int wm = (w >> 1) * 32, wn = (w & 1) * 64;
    const int lr = lane & 15, q = lane >> 4;
    f32x4 acc[2][4] = {};

    STAGE64(0, 0);
    __syncthreads();
    int cur = 0;
    for (int k0 = 0; k0 < CDIM; k0 += 64) {
        if (k0 + 64 < CDIM) STAGE64(cur ^ 1, k0 + 64);
        const int base = cur * 12288;
#pragma unroll
        for (int kk = 0; kk < 2; ++kk) {
            s16x8 af[2], bfr[4];
#pragma unroll
            for (int i = 0; i < 2; ++i) {
                const int r = wm + i * 16 + lr;
                af[i] = *(const s16x8*)&lds[base + r * 64 + ((((kk << 2) | q) ^ (r & 7)) << 3)];
            }
#pragma unroll
            for (int j = 0; j < 4; ++j) {
                const int r = 64 + wn + j * 16 + lr;
                bfr[j] = *(const s16x8*)&lds[base + r * 64 + ((((kk << 2) | q) ^ (r & 7)) << 3)];
            }
#pragma unroll
            for (int i = 0; i < 2; ++i)
#pragma unroll
                for (int j = 0; j < 4; ++j)
                    acc[i][j] = __builtin_amdgcn_mfma_f32_16x16x32_bf16(af[i], bfr[j], acc[i][j], 0, 0, 0);
        }
        __syncthreads();
        cur ^= 1;
    }
#undef STAGE64

    const int lrr = (lane >> 4) * 4;
    const int lc = lane & 15;
#pragma unroll
    for (int j = 0; j < 4; ++j) {
        const int col = col0 + wn + j * 16 + lc;
        const float bv = bias ? bias[col] : 0.f;
#pragma unroll
        for (int i = 0; i < 2; ++i) {
#pragma unroll
            for (int r = 0; r < 4; ++r) {
                const int row = row0 + wm + i * 16 + lrr + r;
                if (row >= M) continue;
                const float v = acc[i][j][r] + bv;
                if (EPI == 0)
                    ((ushort*)Out)[(size_t)row * ldo + col] = f2bf(v);
                else if (EPI == 1)
                    ((ushort*)Out)[(size_t)row * ldo + col] = f2bf(gelu_f(v));
                else {
                    float* p = (float*)Out + (size_t)row * ldo + col;
                    *p = resid[(size_t)row * ldo + col] * rscale + v;
                }
            }
        }
    }
}

// ---------------- MFMA banded rel-pos attention, async-pipelined ----------------
// LDS 51.2 KB -> 3 blocks/CU.  Kl[176][64] (XOR-swizzled, gload_lds) @0;
// Pl[64][200] @0 (aliases Kl after QK phase); Vsub[2][192][16] @25600 (pass A
// direct-gload at start, pass B reg-staged and written after pass-A PV);
// Bd[4][16][104] @37888.  rel_shift identity: u = j - tloc, p row = 949 + u.
__global__ __launch_bounds__(256, 3) void attn_mfma(
    const ushort* __restrict__ qkv, const ushort* __restrict__ pb,
    const float* __restrict__ pos_u, const float* __restrict__ pos_v,
    ushort* __restrict__ o) {
    __shared__ __align__(16) char smem[51200];
    ushort* Kl   = (ushort*)smem;               // [176][64] swizzled
    ushort* Pl   = (ushort*)smem;               // phase2 [64][200]
    ushort* Vsub = (ushort*)(smem + 25600);     // [2][192][16]
    ushort* Bd   = (ushort*)(smem + 37888);     // [4][16][104]

    const int tid = threadIdx.x;
    const int w = tid >> 6, lane = tid & 63;
    const int t0 = blockIdx.x * 64;
    const int h = blockIdx.y, b = blockIdx.z;
    const int m0 = w * 16;
    const int lr = lane & 15, lk = (lane >> 4) * 8, q = lane >> 4;

    // ---- V source address helper (span sp covers 1024 B of [d0][192][16]) ----
    auto vsrc = [&](int sp) -> const ushort* {
        const int ob = sp * 1024 + lane * 16;
        const int d0c = ob / 6144;
        const int rem = ob - d0c * 6144;
        const int j = rem >> 5;
        const int halfo = (rem & 31) >> 4;
        int t = t0 - HALFW + j; t = t < 0 ? 0 : (t < TSEQ ? t : TSEQ - 1);
        return qkv + (size_t)(b * TSEQ + t) * QKVDIM + 2 * CDIM + h * DKK
               + (d0c & 1) * 16 + halfo * 8;
    };

    // ---- (1) oldest VMEM: Q fragments + pos vectors (needed pre-barrier) ----
    int tq = t0 + m0 + lr; tq = tq < TSEQ ? tq : TSEQ - 1;
    const ushort* qp = qkv + (size_t)(b * TSEQ + tq) * QKVDIM + h * DKK;
    s16x8 qr0 = *(const s16x8*)(qp + lk);
    s16x8 qr1 = *(const s16x8*)(qp + 32 + lk);
    const float* puB = pos_u + h * DKK;
    const float* pvB = pos_v + h * DKK;
    float puA[16], pvA[16];
    *(float4*)&puA[0]  = *(const float4*)(puB + lk);
    *(float4*)&puA[4]  = *(const float4*)(puB + lk + 4);
    *(float4*)&puA[8]  = *(const float4*)(puB + 32 + lk);
    *(float4*)&puA[12] = *(const float4*)(puB + 32 + lk + 4);
    *(float4*)&pvA[0]  = *(const float4*)(pvB + lk);
    *(float4*)&pvA[4]  = *(const float4*)(pvB + lk + 4);
    *(float4*)&pvA[8]  = *(const float4*)(pvB + 32 + lk);
    *(float4*)&pvA[12] = *(const float4*)(pvB + 32 + lk + 4);

    // ---- (2) rel-pos B-fragments straight from global (L2-hot) ----
    const ushort* pbh = pb + (size_t)949 * CDIM + h * DKK;
    s16x8 pfr[7][2];
#pragma unroll
    for (int uf = 0; uf < 7; ++uf) {
        pfr[uf][0] = *(const s16x8*)&pbh[(size_t)(uf * 16 + lr) * CDIM + lk];
        pfr[uf][1] = *(const s16x8*)&pbh[(size_t)(uf * 16 + lr) * CDIM + 32 + lk];
    }

    // ---- (3) V pass-A: 12 spans (d0 blocks 0,1) direct to LDS ----
#pragma unroll
    for (int g = 0; g < 3; ++g) {
        const int sp = w * 3 + g;
        gload_lds16(vsrc(sp), (char*)Vsub + sp * 1024);
    }

    // ---- (4) K: 22 gload_lds spans, XOR-swizzled source ----
    {
        const int srow8 = lane >> 3;
        const int schunk = (lane & 7) ^ srow8;
#pragma unroll
        for (int g = 0; g < 6; ++g) {
            const int sp = w * 6 + g;
            if (sp < 22) {
                const int r = sp * 8 + srow8;
                int kb = t0 - HALFW + r; kb = kb < 0 ? 0 : (kb < TSEQ ? kb : TSEQ - 1);
                const ushort* src = qkv + (size_t)(b * TSEQ + kb) * QKVDIM + CDIM
                                    + h * DKK + schunk * 8;
                gload_lds16(src, (char*)Kl + sp * 1024);
            }
        }
    }

    // ---- build qu/qv fragments in regs (waits Q+pos only; K/V stay in flight) ----
    s16x8 qu0, qu1, qv0, qv1;
#pragma unroll
    for (int e = 0; e < 8; ++e) {
        const float q0 = bf2f((ushort)qr0[e]), q1 = bf2f((ushort)qr1[e]);
        qu0[e] = (short)f2bf(q0 + puA[e]);
        qu1[e] = (short)f2bf(q1 + puA[8 + e]);
        qv0[e] = (short)f2bf(q0 + pvA[e]);
        qv1[e] = (short)f2bf(q1 + pvA[8 + e]);
    }
    __syncthreads();   // drains K + V-A gloads

    // ---- score MFMAs ----
    const f32x4 zero = {0.f, 0.f, 0.f, 0.f};
    f32x4 acS[11], acB[7];
    __builtin_amdgcn_s_setprio(1);
#pragma unroll
    for (int uf = 0; uf < 7; ++uf) {
        acB[uf] = __builtin_amdgcn_mfma_f32_16x16x32_bf16(qv0, pfr[uf][0], zero, 0, 0, 0);
        acB[uf] = __builtin_amdgcn_mfma_f32_16x16x32_bf16(qv1, pfr[uf][1], acB[uf], 0, 0, 0);
    }
#pragma unroll
    for (int jf = 0; jf < 11; ++jf) {
        const int rr = jf * 16 + lr;
        const int sw = rr & 7;
        s16x8 k0 = *(const s16x8*)&Kl[rr * 64 + (((q)     ^ sw) << 3)];
        s16x8 k1 = *(const s16x8*)&Kl[rr * 64 + (((q | 4) ^ sw) << 3)];
        acS[jf] = __builtin_amdgcn_mfma_f32_16x16x32_bf16(qu0, k0, zero, 0, 0, 0);
        acS[jf] = __builtin_amdgcn_mfma_f32_16x16x32_bf16(qu1, k1, acS[jf], 0, 0, 0);
    }
    __builtin_amdgcn_s_setprio(0);

    // ---- bd -> LDS (own-wave region) ----
    ushort* bdw = Bd + w * 16 * 104;
#pragma unroll
    for (int uf = 0; uf < 7; ++uf)
#pragma unroll
        for (int r = 0; r < 4; ++r)
            bdw[((lane >> 4) * 4 + r) * 104 + uf * 16 + lr] = f2bf(acB[uf][r]);
    // ---- combine + masked softmax (deferred 1/sum) ----
    float mx[4] = {-1e30f, -1e30f, -1e30f, -1e30f};
#pragma unroll
    for (int jf = 0; jf < 11; ++jf)
#pragma unroll
        for (int r = 0; r < 4; ++r) {
            const int tl = (lane >> 4) * 4 + r;
            const int tloc = m0 + tl;
            const int j = jf * 16 + lr;
            const int u = j - tloc;
            const int s = t0 - HALFW + j;
            const bool valid = (u >= 0) & (u <= 2 * HALFW) & (s >= 0) & (s < TSEQ)
                               & (t0 + tloc < TSEQ);
            float sc = -1e30f;
            if (valid) sc = (acS[jf][r] + bf2f(bdw[tl * 104 + u])) * 0.125f;
            acS[jf][r] = sc;
            mx[r] = fmaxf(mx[r], sc);
        }
#pragma unroll
    for (int r = 0; r < 4; ++r)
#pragma unroll
        for (int off = 8; off; off >>= 1)
            mx[r] = fmaxf(mx[r], __shfl_xor(mx[r], off));
    float sm[4] = {0.f, 0.f, 0.f, 0.f};
#pragma unroll
    for (int jf = 0; jf < 11; ++jf)
#pragma unroll
        for (int r = 0; r < 4; ++r) {
            float e = __expf(acS[jf][r] - mx[r]);
            acS[jf][r] = e;
            sm[r] += e;
        }
#pragma unroll
    for (int r = 0; r < 4; ++r) {
#pragma unroll
        for (int off = 8; off; off >>= 1) sm[r] += __shfl_xor(sm[r], off);
        sm[r] = 1.f / sm[r];
    }
    __syncthreads();   // Kl dead -> Pl region free

    // ---- issue V pass-B loads to regs (consumed after pass-A PV) ----
    s16x8 vr0 = *vsrc(12 + w * 3 + 0);
    s16x8 vr1 = *vsrc(12 + w * 3 + 1);
    s16x8 vr2 = *vsrc(12 + w * 3 + 2);

    // ---- write P (A-frag layout, own rows) + zero pad cols [176,192) ----
#pragma unroll
    for (int jf = 0; jf < 11; ++jf)
#pragma unroll
        for (int r = 0; r < 4; ++r)
            Pl[(m0 + (lane >> 4) * 4 + r) * 200 + jf * 16 + lr] = f2bf(acS[jf][r]);
#pragma unroll
    for (int r = 0; r < 4; ++r)
        Pl[(m0 + (lane >> 4) * 4 + r) * 200 + 176 + lr] = 0;

    // ---- P A-fragments (own rows; intra-wave RAW ordered by lgkmcnt) ----
    s16x8 pa[6];
#pragma unroll
    for (int ks = 0; ks < 6; ++ks)
        pa[ks] = *(const s16x8*)&Pl[(m0 + lr) * 200 + ks * 32 + lk];

    const unsigned vbase = LDSOFF(Vsub);
    // ---- PV pass A: d0 blocks 0,1 ----
#pragma unroll
    for (int nf = 0; nf < 2; ++nf) {
        const unsigned abase = vbase + (nf & 1) * 6144 + ((lane >> 4) << 8) + ((lane & 15) << 1);
        s16x4 lo[6], hi[6];
#pragma unroll
        for (int ks = 0; ks < 6; ++ks) {
            lo[ks] = tr_read(abase + ks * 1024);
            hi[ks] = tr_read128(abase + ks * 1024);
        }
        asm volatile("s_waitcnt lgkmcnt(0)" ::: "memory");
        __builtin_amdgcn_sched_barrier(0);
        f32x4 acO = {};
        __builtin_amdgcn_s_setprio(1);
#pragma unroll
        for (int ks = 0; ks < 6; ++ks) {
            s16x8 vb = __builtin_shufflevector(lo[ks], hi[ks], 0, 1, 2, 3, 4, 5, 6, 7);
            acO = __builtin_amdgcn_mfma_f32_16x16x32_bf16(pa[ks], vb, acO, 0, 0, 0);
        }
        __builtin_amdgcn_s_setprio(0);
#pragma unroll
        for (int r = 0; r < 4; ++r) {
            const int t = t0 + m0 + (lane >> 4) * 4 + r;
            if (t < TSEQ)
                o[(size_t)(b * TSEQ + t) * CDIM + h * DKK + nf * 16 + lr] =
                    f2bf(acO[r] * sm[r]);
        }
    }
    __syncthreads();   // all waves done reading pass-A V

    // ---- write V pass-B from regs ----
    *(s16x8*)((char*)Vsub + (w * 3 + 0) * 1024 + lane * 16) = vr0;
    *(s16x8*)((char*)Vsub + (w * 3 + 1) * 1024 + lane * 16) = vr1;
    *(s16x8*)((char*)Vsub + (w * 3 + 2) * 1024 + lane * 16) = vr2;
    __syncthreads();

    // ---- PV pass B: d0 blocks 2,3 ----
#pragma unroll
    for (int nf = 2; nf < 4; ++nf) {
        const unsigned abase = vbase + (nf & 1) * 6144 + ((lane >> 4) << 8) + ((lane & 15) << 1);
        s16x4 lo[6], hi[6];
#pragma unroll
        for (int ks = 0; ks < 6; ++ks) {
            lo[ks] = tr_read(abase + ks * 1024);
            hi[ks] = tr_read128(abase + ks * 1024);
        }
        asm volatile("s_waitcnt lgkmcnt(0)" ::: "memory");
        __builtin_amdgcn_sched_barrier(0);
        f32x4 acO = {};
        __builtin_amdgcn_s_setprio(1);
#pragma unroll
        for (int ks = 0; ks < 6; ++ks) {
            s16x8 vb = __builtin_shufflevector(lo[ks], hi[ks], 0, 1, 2, 3, 4, 5, 6, 7);
            acO = __builtin_amdgcn_mfma_f32_16x16x32_bf16(pa[ks], vb, acO, 0, 0, 0);
        }
        __builtin_amdgcn_s_setprio(0);
#pragma unroll
        for (int r = 0; r < 4; ++r) {
            const int t = t0 + m0 + (lane >> 4) * 4 + r;
            if (t < TSEQ)
                o[(size_t)(b * TSEQ + t) * CDIM + h * DKK + nf * 16 + lr] =
                    f2bf(acO[r] * sm[r]);
        }
    }
}

// ---------------- launch ----------------
extern "C" void kernel_launch(void* const* d_in, const int* in_sizes, int n_in,
                              void* d_out, int out_size, void* d_ws, size_t ws_size,
                              hipStream_t stream) {
    const float* x     = (const float*)d_in[0];
    const float* Wq    = (const float*)d_in[1];
    const float* bq    = (const float*)d_in[2];
    const float* Wk    = (const float*)d_in[3];
    const float* bk    = (const float*)d_in[4];
    const float* Wv    = (const float*)d_in[5];
    const float* bv    = (const float*)d_in[6];
    const float* Wo    = (const float*)d_in[7];
    const float* bo    = (const float*)d_in[8];
    const float* Wp    = (const float*)d_in[9];
    const float* pos_u = (const float*)d_in[10];
    const float* pos_v = (const float*)d_in[11];
    const float* ln1g  = (const float*)d_in[12];
    const float* ln1b  = (const float*)d_in[13];
    const float* ln2g  = (const float*)d_in[14];
    const float* ln2b  = (const float*)d_in[15];
    const float* W1    = (const float*)d_in[16];
    const float* b1    = (const float*)d_in[17];
    const float* W2    = (const float*)d_in[18];
    const float* b2    = (const float*)d_in[19];

    float* h = (float*)d_out;
    const float XS = 27.712812921102035f;   // sqrt(768)

    char* p = (char*)d_ws;
    ushort* Wtqkv = (ushort*)p;               p += (size_t)LNUM * QKVDIM * CDIM * 2;
    ushort* Wtp   = (ushort*)p;               p += (size_t)LNUM * CDIM * CDIM * 2;
    ushort* Wto   = (ushort*)p;               p += (size_t)LNUM * CDIM * CDIM * 2;
    ushort* Wt1   = (ushort*)p;               p += (size_t)LNUM * CDIM * CDIM * 2;
    ushort* Wt2   = (ushort*)p;               p += (size_t)LNUM * CDIM * CDIM * 2;
    float*  bqkv  = (float*)p;                p += (size_t)LNUM * QKVDIM * 4;
    ushort* pe    = (ushort*)p;               p += (size_t)2048 * CDIM * 2;
    ushort* pb    = (ushort*)p;               p += (size_t)LNUM * 2048 * CDIM * 2;
    ushort* y     = (ushort*)p;               p += (size_t)MPAD * CDIM * 2;
    ushort* qkv   = (ushort*)p;               p += (size_t)MPAD * QKVDIM * 2;
    ushort* o     = (ushort*)p;               p += (size_t)MPAD * CDIM * 2;
    ushort* hid   = (ushort*)p;               p += (size_t)MPAD * CDIM * 2;

    transpose_pack<<<dim3(24, 24, LNUM * 7), dim3(32, 8), 0, stream>>>(
        Wq, Wk, Wv, Wp, Wo, W1, W2, Wtqkv, Wtp, Wto, Wt1, Wt2);
    prep_small<<<384, 256, 0, stream>>>(pe, bq, bk, bv, bqkv);

    const int MB = (MROWS + 63) / 64;        // 63 row-blocks
    const dim3 gQKV(MB, QKVDIM / 128);       // (63, 18)
    const dim3 gC(MB, CDIM / 128);           // (63, 6)
    const dim3 gP(4, CDIM / 128, LNUM);      // M=256 rel-pos rows, both layers
    const dim3 gA(16, HHEADS, BBATCH);

    gemm64<0><<<gP, 256, 0, stream>>>(pe + (size_t)896 * CDIM, Wtp, nullptr,
                                      pb + (size_t)896 * CDIM, 256, CDIM,
                                      nullptr, 0.f,
                                      (size_t)CDIM * CDIM, (size_t)2048 * CDIM);

    for (int l = 0; l < LNUM; ++l) {
        const size_t wo = (size_t)l * CDIM * CDIM;
        const float* res1 = (l == 0) ? x : h;
        const float rs1   = (l == 0) ? XS : 1.f;
        ln_kernel<<<MROWS, 192, 0, stream>>>(res1, ln1g + l * CDIM, ln1b + l * CDIM, y, rs1);
        gemm64<0><<<gQKV, 256, 0, stream>>>(y, Wtqkv + (size_t)l * QKVDIM * CDIM,
                                            bqkv + l * QKVDIM, qkv, MROWS, QKVDIM,
                                            nullptr, 0.f, 0, 0);
        attn_mfma<<<gA, 256, 0, stream>>>(
            qkv, pb + (size_t)l * 2048 * CDIM,
            pos_u + l * HHEADS * DKK, pos_v + l * HHEADS * DKK, o);
        gemm64<2><<<gC, 256, 0, stream>>>(o, Wto + wo, bo + l * CDIM, h, MROWS, CDIM,
                                          res1, rs1, 0, 0);
        ln_kernel<<<MROWS, 192, 0, stream>>>(h, ln2g + l * CDIM, ln2b + l * CDIM, y, 1.f);
        gemm64<1><<<gC, 256, 0, stream>>>(y, Wt1 + wo, b1 + l * CDIM, hid, MROWS, CDIM,
                                          nullptr, 0.f, 0, 0);
        gemm64<2><<<gC, 256, 0, stream>>>(hid, Wt2 + wo, b2 + l * CDIM, h, MROWS, CDIM,
                                          h, 1.f, 0, 0);
    }
}